// Round 21
// baseline (1545.015 us; speedup 1.0000x reference)
//
#include <hip/hip_runtime.h>
#include <hip/hip_bf16.h>

#define Bc 4
#define Cc 128
#define Nn 4096
#define INFF 3.4e38f

// ---------------------------------------------------------------------------
// K1: sq[b*N + n] = sum_c x[b][c][n]^2, sequential ascending FMA chain.
// MUST match the Gram accumulation chain bitwise so self-distance == 0.
// ---------------------------------------------------------------------------
__global__ void k_sq(const float* __restrict__ x, float* __restrict__ sq) {
    int id = blockIdx.x * 256 + threadIdx.x;          // 16384 total
    int b = id >> 12, n = id & (Nn - 1);
    const float* xb = x + (size_t)b * Cc * Nn + n;
    float a = 0.f;
    #pragma unroll 8
    for (int c = 0; c < Cc; ++c) {
        float v = xb[(size_t)c * Nn];
        a = fmaf(v, v, a);
    }
    sq[id] = a;
}

// sorted-ascending top-9 insert (single list, static indices -> reg-safe).
__device__ __forceinline__ void insert9(float (&d)[9], int (&ix)[9], float nd, int ni) {
    float cx = nd; int cI = ni;
    #pragma unroll
    for (int p = 0; p < 9; ++p) {
        bool lt = cx < d[p];
        float td = d[p]; int ti = ix[p];
        if (lt) { d[p] = cx; ix[p] = cI; cx = td; cI = ti; }
    }
}

// staging chunk swizzle (proven r13+): LDS linear via gload_lds, source
// chunk inverse-swizzled; compute reads <=2-way conflicted.
__device__ __forceinline__ int swz(int q)   { return (q & 24) | ((q + (q >> 3)) & 7); }
__device__ __forceinline__ int swz16(int q) { return (q & 8)  | ((q + (q >> 3)) & 7); }

__device__ __forceinline__ void gload16(const float* g, float* l) {
    __builtin_amdgcn_global_load_lds(
        (const __attribute__((address_space(1))) void*)g,
        (__attribute__((address_space(3))) void*)l, 16, 0, 0);
}

// argmin over the 16-lane group (lanes 16-aligned; xor m<16 stays in group)
#define GROUP_ARGMIN(v, ix)                                   \
    _Pragma("unroll")                                         \
    for (int m_ = 1; m_ < 16; m_ <<= 1) {                     \
        float ov_ = __shfl_xor((v), m_);                      \
        int   oi_ = __shfl_xor((ix), m_);                     \
        bool tk_ = (ov_ < (v)) || (ov_ == (v) && oi_ < (ix)); \
        (v)  = tk_ ? ov_ : (v);                               \
        (ix) = tk_ ? oi_ : (ix);                              \
    }

// argmin over the 4 same-tx lanes of one wave (xor 16, 32)
#define COL_ARGMIN(v, ix)                                     \
    _Pragma("unroll")                                         \
    for (int m_ = 16; m_ < 64; m_ <<= 1) {                    \
        float ov_ = __shfl_xor((v), m_);                      \
        int   oi_ = __shfl_xor((ix), m_);                     \
        bool tk_ = (ov_ < (v)) || (ov_ == (v) && oi_ < (ix)); \
        (v)  = tk_ ? ov_ : (v);                               \
        (ix) = tk_ ? oi_ : (ix);                              \
    }

#define LMIN8 { lv = da.x; ls = 0;                                       \
    { bool tk = da.y < lv; lv = tk ? da.y : lv; ls = tk ? 1 : ls; }      \
    { bool tk = da.z < lv; lv = tk ? da.z : lv; ls = tk ? 2 : ls; }      \
    { bool tk = da.w < lv; lv = tk ? da.w : lv; ls = tk ? 3 : ls; }      \
    { bool tk = db.x < lv; lv = tk ? db.x : lv; ls = tk ? 4 : ls; }      \
    { bool tk = db.y < lv; lv = tk ? db.y : lv; ls = tk ? 5 : ls; }      \
    { bool tk = db.z < lv; lv = tk ? db.z : lv; ls = tk ? 6 : ls; }      \
    { bool tk = db.w < lv; lv = tk ? db.w : lv; ls = tk ? 7 : ls; } }
#define MASKSLOT { da.x = (ls == 0) ? INFF : da.x;                       \
    da.y = (ls == 1) ? INFF : da.y;  da.z = (ls == 2) ? INFF : da.z;     \
    da.w = (ls == 3) ? INFF : da.w;  db.x = (ls == 4) ? INFF : db.x;     \
    db.y = (ls == 5) ? INFF : db.y;  db.z = (ls == 6) ? INFF : db.z;     \
    db.w = (ls == 7) ? INFF : db.w; }

// ---------------------------------------------------------------------------
// K2: symmetric Gram tile + fused top-9 selection (no G materialization).
// GEMM core byte-identical to r18's passing 32KB-dbuf kernel (chain
// c ascending == k_sq bitwise -> diagonal d2 exactly 0).
// r19's col-side LDS transpose (buggy: o1 landed at roff+8) is REPLACED by
// per-wave reduction: wave w owns contiguous rows [rowbase+w*32, +32); a
// column's in-wave owners are the 4 lanes {tyl*16+tx} -> shfl_xor {16,32}.
// Each (col,wave) 9-list -> 36KB LDS table -> in-kernel 4-way merge
// (ascending w = ascending row chunks, strict-< insert9) -> pdc slot ri.
// Row-side: rows owned by 16 consecutive lanes -> shfl_xor {1..8} -> pdr
// slot ci. Every lane uses its OWN rn/cn (no cross-lane norm mixups).
// ---------------------------------------------------------------------------
__global__ __launch_bounds__(256, 2) void k_gemm_sel(
        const float* __restrict__ xb, const float* __restrict__ sqb,
        float* __restrict__ pdr, int* __restrict__ pir,
        float* __restrict__ pdc, int* __restrict__ pic) {
    __shared__ alignas(16) float smem[9216];   // 36KB: staging [0,8192); lists

    const int t  = threadIdx.x;
    const int tx = t & 15;
    const int ty = t >> 4;

    // triangular decode: bid -> (ri, ci), ri <= ci
    int rem = blockIdx.x;
    int ri = 0;
    while (rem >= 32 - ri) { rem -= 32 - ri; ++ri; }
    const int ci = ri + rem;
    const int rowbase = ri * 128;
    const int colbase = ci * 128;

    auto STAGE = [&](int st, int buf) {
        const int c0 = st * 16;
        float* Ab = smem + (buf ? 2048 : 0);
        float* Bb = smem + 4096 + (buf ? 2048 : 0);
        #pragma unroll
        for (int j = 0; j < 2; ++j) {         // A: 512 float4
            int f = j * 256 + t;
            int cl = f >> 5, q = f & 31;
            int qi = (q & 24) | ((q - (q >> 3)) & 7);  // inv of swz
            gload16(&xb[(size_t)(c0 + cl) * Nn + rowbase + qi * 4],
                    &Ab[(f & ~63) * 4]);
        }
        #pragma unroll
        for (int j = 0; j < 2; ++j) {         // B: 512 float4
            int f = j * 256 + t;
            int cl = f >> 5, q = f & 31;
            int qi = (q & 24) | ((q - (q >> 3)) & 7);
            gload16(&xb[(size_t)(c0 + cl) * Nn + colbase + qi * 4],
                    &Bb[(f & ~63) * 4]);
        }
    };

    float acc[8][8];
    #pragma unroll
    for (int i = 0; i < 8; ++i)
        #pragma unroll
        for (int j = 0; j < 8; ++j) acc[i][j] = 0.f;

    const int ra0 = swz(ty * 2), ra1 = swz(ty * 2 + 1);
    const int rb0 = swz(tx * 2), rb1 = swz(tx * 2 + 1);

    STAGE(0, 0);
    for (int s = 0; s < 8; ++s) {
        const int buf = s & 1;
        __syncthreads();          // drains vmcnt -> buf landed; syncs block
        if (s < 7) STAGE(s + 1, buf ^ 1);

        const float4* A4 = (const float4*)(smem + (buf ? 2048 : 0));
        const float4* B4 = (const float4*)(smem + 4096 + (buf ? 2048 : 0));
        #pragma unroll
        for (int cl = 0; cl < 16; ++cl) {
            float4 a0 = A4[cl * 32 + ra0];
            float4 a1 = A4[cl * 32 + ra1];
            float4 b0 = B4[cl * 32 + rb0];
            float4 b1 = B4[cl * 32 + rb1];
            float av[8] = {a0.x, a0.y, a0.z, a0.w, a1.x, a1.y, a1.z, a1.w};
            float bv[8] = {b0.x, b0.y, b0.z, b0.w, b1.x, b1.y, b1.z, b1.w};
            #pragma unroll
            for (int i = 0; i < 8; ++i)
                #pragma unroll
                for (int j = 0; j < 8; ++j)
                    acc[i][j] = fmaf(av[i], bv[j], acc[i][j]); // c-ascending
        }
    }

    // norms (this lane's own rows/cols)
    float4 rnA = *(const float4*)&sqb[rowbase + ty * 8];
    float4 rnB = *(const float4*)&sqb[rowbase + ty * 8 + 4];
    float4 cnA = *(const float4*)&sqb[colbase + tx * 8];
    float4 cnB = *(const float4*)&sqb[colbase + tx * 8 + 4];

    // ---------------- row-side: slot ci, output rows of block ri ----------
    #pragma unroll
    for (int i = 0; i < 8; ++i) {
        float rni = (i == 0) ? rnA.x : (i == 1) ? rnA.y : (i == 2) ? rnA.z :
                    (i == 3) ? rnA.w : (i == 4) ? rnB.x : (i == 5) ? rnB.y :
                    (i == 6) ? rnB.z : rnB.w;
        float4 da, db;
        da.x = fmaf(-2.f, acc[i][0], rni + cnA.x);
        da.y = fmaf(-2.f, acc[i][1], rni + cnA.y);
        da.z = fmaf(-2.f, acc[i][2], rni + cnA.z);
        da.w = fmaf(-2.f, acc[i][3], rni + cnA.w);
        db.x = fmaf(-2.f, acc[i][4], rni + cnB.x);
        db.y = fmaf(-2.f, acc[i][5], rni + cnB.y);
        db.z = fmaf(-2.f, acc[i][6], rni + cnB.z);
        db.w = fmaf(-2.f, acc[i][7], rni + cnB.w);

        float lv; int ls;
        LMIN8
        int lc = colbase + tx * 8 + ls;
        int row = rowbase + ty * 8 + i;
        #pragma unroll
        for (int k = 0; k < 9; ++k) {
            float v = lv; int ix = lc;
            GROUP_ARGMIN(v, ix)
            if (tx == 0) {
                pdr[((size_t)ci * 9 + k) * Nn + row] = v;
                pir[((size_t)ci * 9 + k) * Nn + row] = ix;
            }
            if (lc == ix) { MASKSLOT LMIN8 lc = colbase + tx * 8 + ls; }
        }
    }

    // ---------------- col-side (off-diag): slot ri, output rows of ci -----
    if (ri != ci) {
        __syncthreads();                      // staging reads done; reuse smem
        const int w   = t >> 6;               // wave: rows rowbase+w*32..+32
        const int tyl = (t >> 4) & 3;
        #pragma unroll
        for (int j = 0; j < 8; ++j) {
            float cgn = (j == 0) ? cnA.x : (j == 1) ? cnA.y : (j == 2) ? cnA.z :
                        (j == 3) ? cnA.w : (j == 4) ? cnB.x : (j == 5) ? cnB.y :
                        (j == 6) ? cnB.z : cnB.w;
            float4 da, db;
            da.x = fmaf(-2.f, acc[0][j], cgn + rnA.x);
            da.y = fmaf(-2.f, acc[1][j], cgn + rnA.y);
            da.z = fmaf(-2.f, acc[2][j], cgn + rnA.z);
            da.w = fmaf(-2.f, acc[3][j], cgn + rnA.w);
            db.x = fmaf(-2.f, acc[4][j], cgn + rnB.x);
            db.y = fmaf(-2.f, acc[5][j], cgn + rnB.y);
            db.z = fmaf(-2.f, acc[6][j], cgn + rnB.z);
            db.w = fmaf(-2.f, acc[7][j], cgn + rnB.w);

            float lv; int ls;
            LMIN8
            int lc = rowbase + ty * 8 + ls;
            const int cgl = tx * 8 + j;       // col within tile, 0..127
            #pragma unroll
            for (int k = 0; k < 9; ++k) {
                float v = lv; int ix = lc;
                COL_ARGMIN(v, ix)
                if (tyl == 0) {
                    smem[(cgl * 4 + w) * 18 + k * 2]     = v;
                    smem[(cgl * 4 + w) * 18 + k * 2 + 1] = __int_as_float(ix);
                }
                if (lc == ix) { MASKSLOT LMIN8 lc = rowbase + ty * 8 + ls; }
            }
        }
        __syncthreads();
        if (t < 128) {                        // merge 4 wave-lists of col t
            float d0[9]; int i0[9];
            #pragma unroll
            for (int k = 0; k < 9; ++k) {
                d0[k] = smem[(t * 4 + 0) * 18 + k * 2];
                i0[k] = __float_as_int(smem[(t * 4 + 0) * 18 + k * 2 + 1]);
            }
            #pragma unroll
            for (int w2 = 1; w2 < 4; ++w2)
                #pragma unroll
                for (int k = 0; k < 9; ++k) {
                    float dv = smem[(t * 4 + w2) * 18 + k * 2];
                    if (dv < d0[8])
                        insert9(d0, i0, dv,
                                __float_as_int(smem[(t * 4 + w2) * 18 + k * 2 + 1]));
                }
            int cg = colbase + t;
            #pragma unroll
            for (int k = 0; k < 9; ++k) {
                pdc[((size_t)ri * 9 + k) * Nn + cg] = d0[k];
                pic[((size_t)ri * 9 + k) * Nn + cg] = i0[k];
            }
        }
    }
}

// ---------------------------------------------------------------------------
// K2b: per row n (block rb), merge exactly 32 sorted lists: pdc[s] for
// s<rb (candidates in block s, via tile (s,rb) col-side), then pdr[s] for
// s>=rb (tile (rb,s) row-side). Ascending s = ascending candidate cols +
// strict-< insertion => jax.lax.top_k tie-break preserved.
// ---------------------------------------------------------------------------
__global__ void k_merge2x32(const float* __restrict__ pdr, const int* __restrict__ pir,
                            const float* __restrict__ pdc, const int* __restrict__ pic,
                            int* __restrict__ idxOut, int b) {
    int row = blockIdx.x * 256 + threadIdx.x;  // 4096 rows
    int rb = row >> 7;
    float d0[9]; int i0[9];
    #pragma unroll
    for (int k = 0; k < 9; ++k) { d0[k] = INFF; i0[k] = 0x7fffffff; }
    for (int s = 0; s < rb; ++s) {
        for (int k = 0; k < 9; ++k) {
            float dv = pdc[((size_t)s * 9 + k) * Nn + row];
            if (dv < d0[8]) insert9(d0, i0, dv, pic[((size_t)s * 9 + k) * Nn + row]);
            else break;
        }
    }
    for (int s = rb; s < 32; ++s) {
        for (int k = 0; k < 9; ++k) {
            float dv = pdr[((size_t)s * 9 + k) * Nn + row];
            if (dv < d0[8]) insert9(d0, i0, dv, pir[((size_t)s * 9 + k) * Nn + row]);
            else break;
        }
    }
    #pragma unroll
    for (int k = 0; k < 9; ++k)
        idxOut[((size_t)b * 9 + k) * Nn + row] = i0[k];
}

// ===========================================================================
// FALLBACK PATH (r13, proven): fused gram+top9 + merge, if ws too small.
// ===========================================================================
__global__ __launch_bounds__(256, 1) void k_gram_topk(
        const float* __restrict__ x, const float* __restrict__ sq,
        float* __restrict__ pd, int* __restrict__ pi) {
    __shared__ alignas(16) float As[2][32 * 64];    // 2 x 8KB
    __shared__ alignas(16) float Bs[2][32 * 128];   // 2 x 16KB

    const int t  = threadIdx.x;
    const int tx = t & 15;
    const int ty = t >> 4;
    const int bid = blockIdx.x;               // (b*64 + rg)*8 + oct
    const int b   = bid >> 9;
    const int rg  = (bid >> 3) & 63;
    const int oct = bid & 7;
    const int rowbase = rg * 64;
    const int coloct = oct * 512;
    const float* xb  = x + (size_t)b * Cc * Nn;
    const float* sqb = sq + b * Nn;

    float rown[4];
    #pragma unroll
    for (int i = 0; i < 4; ++i) rown[i] = sqb[rowbase + ty * 4 + i];

    float cd[4][9]; int ci[4][9];
    #pragma unroll
    for (int i = 0; i < 4; ++i)
        #pragma unroll
        for (int p = 0; p < 9; ++p) { cd[i][p] = INFF; ci[i][p] = 0; }

    const int ra  = swz16(ty);
    const int rb0 = swz(tx * 2), rb1 = swz(tx * 2 + 1);

    auto STAGE = [&](int s, int buf) {
        const int c0 = (s & 3) * 32;
        const int colbase = coloct + (s >> 2) * 128;
        float* Ab = &As[buf][0];
        float* Bb = &Bs[buf][0];
        #pragma unroll
        for (int j = 0; j < 2; ++j) {
            int f = j * 256 + t;
            int cl = f >> 4, q = f & 15;
            int qi = (q & 8) | ((q - (q >> 3)) & 7);
            gload16(&xb[(size_t)(c0 + cl) * Nn + rowbase + qi * 4],
                    &Ab[(f & ~63) * 4]);
        }
        #pragma unroll
        for (int j = 0; j < 4; ++j) {
            int f = j * 256 + t;
            int cl = f >> 5, q = f & 31;
            int qi = (q & 24) | ((q - (q >> 3)) & 7);
            gload16(&xb[(size_t)(c0 + cl) * Nn + colbase + qi * 4],
                    &Bb[(f & ~63) * 4]);
        }
    };

    STAGE(0, 0);
    float acc[4][8];
    for (int s = 0; s < 16; ++s) {
        const int buf = s & 1;
        __syncthreads();
        if (s < 15) STAGE(s + 1, buf ^ 1);

        if ((s & 3) == 0) {
            #pragma unroll
            for (int i = 0; i < 4; ++i)
                #pragma unroll
                for (int j = 0; j < 8; ++j) acc[i][j] = 0.f;
        }

        const float4* A4 = (const float4*)&As[buf][0];
        const float4* B4 = (const float4*)&Bs[buf][0];
        #pragma unroll 4
        for (int cl = 0; cl < 32; ++cl) {
            float4 a  = A4[cl * 16 + ra];
            float4 b0 = B4[cl * 32 + rb0];
            float4 b1 = B4[cl * 32 + rb1];
            float av[4] = {a.x, a.y, a.z, a.w};
            float bv[8] = {b0.x, b0.y, b0.z, b0.w, b1.x, b1.y, b1.z, b1.w};
            #pragma unroll
            for (int i = 0; i < 4; ++i)
                #pragma unroll
                for (int j = 0; j < 8; ++j)
                    acc[i][j] = fmaf(av[i], bv[j], acc[i][j]);
        }

        if ((s & 3) == 3) {
            const int colbase = coloct + (s >> 2) * 128;
            float4 cn0 = *(const float4*)&sqb[colbase + tx * 8];
            float4 cn1 = *(const float4*)&sqb[colbase + tx * 8 + 4];
            float cn[8] = {cn0.x, cn0.y, cn0.z, cn0.w,
                           cn1.x, cn1.y, cn1.z, cn1.w};
            #pragma unroll
            for (int i = 0; i < 4; ++i)
                #pragma unroll
                for (int j = 0; j < 8; ++j) {
                    float dd = fmaf(-2.0f, acc[i][j], rown[i] + cn[j]);
                    if (dd < cd[i][8])
                        insert9(cd[i], ci[i], dd, colbase + tx * 8 + j);
                }
        }
    }

    #pragma unroll
    for (int m = 1; m < 16; m <<= 1) {
        #pragma unroll
        for (int i = 0; i < 4; ++i) {
            float od[9]; int oi[9];
            #pragma unroll
            for (int p = 0; p < 9; ++p) {
                od[p] = __shfl_xor(cd[i][p], m);
                oi[p] = __shfl_xor(ci[i][p], m);
            }
            #pragma unroll
            for (int p = 0; p < 9; ++p)
                if (od[p] < cd[i][8]) insert9(cd[i], ci[i], od[p], oi[p]);
        }
    }

    if (tx == 0) {
        #pragma unroll
        for (int i = 0; i < 4; ++i) {
            int n = rowbase + ty * 4 + i;
            #pragma unroll
            for (int k = 0; k < 9; ++k) {
                size_t o = (((size_t)b * 8 + oct) * 9 + k) * Nn + n;
                pd[o] = cd[i][k];
                pi[o] = ci[i][k];
            }
        }
    }
}

__global__ void k_merge(const float* __restrict__ pd, const int* __restrict__ pi,
                        int* __restrict__ idxOut) {
    int id = blockIdx.x * 256 + threadIdx.x;  // 16384
    int b = id >> 12, n = id & (Nn - 1);
    float d0[9]; int i0[9];
    #pragma unroll
    for (int k = 0; k < 9; ++k) {
        size_t o = (((size_t)b * 8 + 0) * 9 + k) * Nn + n;
        d0[k] = pd[o]; i0[k] = pi[o];
    }
    #pragma unroll
    for (int q = 1; q < 8; ++q) {
        #pragma unroll
        for (int k = 0; k < 9; ++k) {
            size_t o = (((size_t)b * 8 + q) * 9 + k) * Nn + n;
            float dv = pd[o]; int iv = pi[o];
            if (dv < d0[8]) insert9(d0, i0, dv, iv);
        }
    }
    #pragma unroll
    for (int k = 0; k < 9; ++k)
        idxOut[((size_t)b * 9 + k) * Nn + n] = i0[k];
}

// ---------------------------------------------------------------------------
// K3: h0[b][c][n] = (1+eps)*x[b][c][n] + sum_k x[b][c][idx[b][k][n]]
// ---------------------------------------------------------------------------
__global__ void k_gather(const float* __restrict__ x, const int* __restrict__ idx,
                         const float* __restrict__ epsp, float* __restrict__ h0) {
    int id = blockIdx.x * 256 + threadIdx.x;          // B*C*N = 2097152
    int n  = id & (Nn - 1);
    int bc = id >> 12;                                // b*C + c
    int b  = bc >> 7;
    const float* xr = x + (size_t)bc * Nn;
    const int* ib = idx + (size_t)b * 9 * Nn + n;
    float s = (1.0f + epsp[0]) * xr[n];
    #pragma unroll
    for (int k = 0; k < 9; ++k) s += xr[ib[(size_t)k * Nn]];
    h0[id] = s;
}

// ---------------------------------------------------------------------------
// K4/K5: out[b][d][n] = act( bias[d] + sum_c W[c][d] * in[b][c][n] )
// ---------------------------------------------------------------------------
template <bool RELU>
__global__ __launch_bounds__(256, 2) void k_mlp(
        const float* __restrict__ in, const float* __restrict__ W,
        const float* __restrict__ bias, float* __restrict__ out) {
    const int t  = threadIdx.x;
    const int td = t & 15;
    const int tn = t >> 4;
    const int bid = blockIdx.x;   // B*2*64 = 512
    const int b = bid >> 7;
    const int dbase = ((bid >> 6) & 1) * 64;
    const int nb = (bid & 63) * 64;

    __shared__ alignas(16) float Ws[128 * 64];
    __shared__ alignas(16) float Hs[128 * 64];

    for (int k = t; k < 128 * 64; k += 256) {
        int i = k & 63; int c = k >> 6;
        int sw = c * 64 + ((((i >> 2) ^ (c & 7)) << 2) | (i & 3));
        Ws[sw] = W[c * 128 + dbase + i];
        Hs[sw] = in[((size_t)b * 128 + c) * Nn + nb + i];
    }
    __syncthreads();

    float acc[4][4];
    #pragma unroll
    for (int dd = 0; dd < 4; ++dd)
        #pragma unroll
        for (int nn = 0; nn < 4; ++nn) acc[dd][nn] = 0.f;

    const float4* W4 = reinterpret_cast<const float4*>(Ws);
    const float4* H4 = reinterpret_cast<const float4*>(Hs);
    for (int c = 0; c < 128; ++c) {
        int cx = c & 7;
        float4 w = W4[c * 16 + (td ^ cx)];
        float4 h = H4[c * 16 + (tn ^ cx)];
        float wf[4] = {w.x, w.y, w.z, w.w};
        float hf[4] = {h.x, h.y, h.z, h.w};
        #pragma unroll
        for (int dd = 0; dd < 4; ++dd)
            #pragma unroll
            for (int nn = 0; nn < 4; ++nn)
                acc[dd][nn] = fmaf(wf[dd], hf[nn], acc[dd][nn]);
    }

    #pragma unroll
    for (int dd = 0; dd < 4; ++dd) {
        int d = dbase + 4 * td + dd;
        float bb = bias[d];
        float4 o;
        o.x = acc[dd][0] + bb; o.y = acc[dd][1] + bb;
        o.z = acc[dd][2] + bb; o.w = acc[dd][3] + bb;
        if (RELU) {
            o.x = fmaxf(o.x, 0.f); o.y = fmaxf(o.y, 0.f);
            o.z = fmaxf(o.z, 0.f); o.w = fmaxf(o.w, 0.f);
        }
        *reinterpret_cast<float4*>(&out[((size_t)b * 128 + d) * Nn + nb + 4 * tn]) = o;
    }
}

// ---------------------------------------------------------------------------
// K6: per-channel batch-norm stats (biased var), 1 block per channel.
// ---------------------------------------------------------------------------
__global__ void k_bnstats(const float* __restrict__ o, const float* __restrict__ gamma,
                          const float* __restrict__ beta, float* __restrict__ scsh) {
    int e = blockIdx.x, t = threadIdx.x;
    float s = 0.f, s2 = 0.f;
    for (int b = 0; b < Bc; ++b) {
        const float* p = o + ((size_t)b * 128 + e) * Nn;
        for (int n = t; n < Nn; n += 256) {
            float v = p[n];
            s += v;
            s2 = fmaf(v, v, s2);
        }
    }
    __shared__ float rs[256], rq[256];
    rs[t] = s; rq[t] = s2;
    __syncthreads();
    for (int off = 128; off > 0; off >>= 1) {
        if (t < off) { rs[t] += rs[t + off]; rq[t] += rq[t + off]; }
        __syncthreads();
    }
    if (t == 0) {
        float mean = rs[0] * (1.0f / 16384.0f);
        float var  = rq[0] * (1.0f / 16384.0f) - mean * mean;
        if (var < 0.f) var = 0.f;
        float sc = gamma[e] * rsqrtf(var + 1e-5f);
        scsh[e] = sc;
        scsh[128 + e] = beta[e] - mean * sc;
    }
}

// ---------------------------------------------------------------------------
// K7: out = relu(scale[e]*o + shift[e] + x), in place on d_out, float4.
// ---------------------------------------------------------------------------
__global__ void k_bnapply(float* __restrict__ o, const float* __restrict__ x,
                          const float* __restrict__ scsh) {
    int id4 = blockIdx.x * 256 + threadIdx.x;         // 524288
    int e = (id4 >> 10) & 127;
    float sc = scsh[e], sh = scsh[128 + e];
    float4 v = reinterpret_cast<const float4*>(o)[id4];
    float4 r = reinterpret_cast<const float4*>(x)[id4];
    float4 w;
    w.x = fmaxf(fmaf(sc, v.x, sh) + r.x, 0.f);
    w.y = fmaxf(fmaf(sc, v.y, sh) + r.y, 0.f);
    w.z = fmaxf(fmaf(sc, v.z, sh) + r.z, 0.f);
    w.w = fmaxf(fmaf(sc, v.w, sh) + r.w, 0.f);
    reinterpret_cast<float4*>(o)[id4] = w;
}

// ---------------------------------------------------------------------------
extern "C" void kernel_launch(void* const* d_in, const int* in_sizes, int n_in,
                              void* d_out, int out_size, void* d_ws, size_t ws_size,
                              hipStream_t stream) {
    const float* x     = (const float*)d_in[0];
    const float* epsp  = (const float*)d_in[1];
    const float* W1    = (const float*)d_in[2];
    const float* b1    = (const float*)d_in[3];
    const float* W2    = (const float*)d_in[4];
    const float* b2    = (const float*)d_in[5];
    const float* gamma = (const float*)d_in[6];
    const float* beta  = (const float*)d_in[7];
    float* out = (float*)d_out;

    // common (floats): sq[16384] | idx[147456] | h0[2097152] | h1[2097152]
    // | scsh[256] = 4358400. Then pdr/pir/pdc/pic: 4 x [32][9][4096]
    // (=1179648 each) = 18.9MB extra; total need ~36.3MB.
    float* ws   = (float*)d_ws;
    float* sq   = ws;
    int*   idx  = (int*)(ws + 16384);
    float* h0   = ws + 16384 + (size_t)Bc * 9 * Nn;
    float* h1   = h0 + (size_t)Bc * Cc * Nn;
    float* scsh = h1 + (size_t)Bc * Cc * Nn;
    float* pdr  = ws + 4358400;
    int*   pir  = (int*)(pdr + 1179648);
    float* pdc  = (float*)(pir + 1179648);
    int*   pic  = (int*)(pdc + 1179648);

    const size_t need = (4358400ull + 4ull * 1179648ull) * 4;  // ~36.3MB

    k_sq <<<64, 256, 0, stream>>>(x, sq);

    if (ws_size >= need) {
        for (int b = 0; b < Bc; ++b) {
            k_gemm_sel <<<528, 256, 0, stream>>>(x + (size_t)b * Cc * Nn,
                                                 sq + (size_t)b * Nn,
                                                 pdr, pir, pdc, pic);
            k_merge2x32<<<16,  256, 0, stream>>>(pdr, pir, pdc, pic, idx, b);
        }
    } else {
        // fallback: r13 fused path; pd aliases h0, pi aliases h1
        float* pd = h0;
        int*   pi = (int*)h1;
        k_gram_topk<<<2048, 256, 0, stream>>>(x, sq, pd, pi);
        k_merge    <<<64,   256, 0, stream>>>(pd, pi, idx);
    }

    k_gather    <<<8192, 256, 0, stream>>>(x, idx, epsp, h0);
    k_mlp<true> <<<512,  256, 0, stream>>>(h0, W1, b1, h1);
    k_mlp<false><<<512,  256, 0, stream>>>(h1, W2, b2, out);
    k_bnstats   <<<128,  256, 0, stream>>>(out, gamma, beta, scsh);
    k_bnapply   <<<2048, 256, 0, stream>>>(out, x, scsh);
}

// Round 22
// 480.235 us; speedup vs baseline: 3.2172x; 3.2172x over previous
//
#include <hip/hip_runtime.h>
#include <hip/hip_bf16.h>

#define Bc 4
#define Cc 128
#define Nn 4096
#define INFF 3.4e38f

// ---------------------------------------------------------------------------
// K1: sq[b*N + n] = sum_c x[b][c][n]^2, sequential ascending FMA chain.
// MUST match the Gram accumulation chain bitwise so self-distance == 0.
// ---------------------------------------------------------------------------
__global__ void k_sq(const float* __restrict__ x, float* __restrict__ sq) {
    int id = blockIdx.x * 256 + threadIdx.x;          // 16384 total
    int b = id >> 12, n = id & (Nn - 1);
    const float* xb = x + (size_t)b * Cc * Nn + n;
    float a = 0.f;
    #pragma unroll 8
    for (int c = 0; c < Cc; ++c) {
        float v = xb[(size_t)c * Nn];
        a = fmaf(v, v, a);
    }
    sq[id] = a;
}

// ---------------------------------------------------------------------------
// sorted-ascending top-9 insert (fallback path only).
// ---------------------------------------------------------------------------
__device__ __forceinline__ void insert9(float (&d)[9], int (&ix)[9], float nd, int ni) {
    float cx = nd; int cI = ni;
    #pragma unroll
    for (int p = 0; p < 9; ++p) {
        bool lt = cx < d[p];
        float td = d[p]; int ti = ix[p];
        if (lt) { d[p] = cx; ix[p] = cI; cx = td; cI = ti; }
    }
}

// Chunk swizzles (rotate within each 8-chunk run by run index) + inverses.
__device__ __forceinline__ int swz(int q)    { return (q & 24) | ((q + (q >> 3)) & 7); }
__device__ __forceinline__ int swz16(int q)  { return (q & 8)  | ((q + (q >> 3)) & 7); }

// global -> LDS direct 16B async copy
__device__ __forceinline__ void gload16(const float* g, float* l) {
    __builtin_amdgcn_global_load_lds(
        (const __attribute__((address_space(1))) void*)g,
        (__attribute__((address_space(3))) void*)l, 16, 0, 0);
}

// ===========================================================================
// TWO-PASS PATH (r18 skeleton, proven 413us): symmetric GEMM -> G, then
// per-row register-only top-9 scan. r21 proved fused selection loses 3.7x
// (serial shfl chains at 1 wave/SIMD). This round: 512-thread gemm blocks
// (2 tiles/block) to GUARANTEE 2 waves/SIMD from one resident block.
// ===========================================================================

// ---------------------------------------------------------------------------
// K2a v4 (SYMMETRIC, 2 tiles per 512-thr block): G[r][c]=sum_ch x[ch][r]x[ch][c].
// r18 evidence: 256-thr blocks -> 1 wave/SIMD -> staging+LDS latency fully
// exposed (VALUBusy 27%, 58us vs ~10us pipe floor); cross-block co-residency
// unreliable at small grids. v4: sub-block s=t>>8 owns tile 2*bid+s with its
// own 32KB LDS half -> 8 waves/block = 2 waves/SIMD guaranteed. Math is
// byte-identical per tile (chain c = st*16+cl ascending == k_sq bitwise ->
// diagonal d2 exactly 0); off-diag tiles dual-stored (fmaf multiply
// commutes -> bitwise symmetric). Grid 264 = 528 tiles / 2.
// ---------------------------------------------------------------------------
__global__ __launch_bounds__(512, 1) void k_gemm2(
        const float* __restrict__ xb, float* __restrict__ G) {
    __shared__ alignas(16) float smem[16384];   // 64KB: 32KB per sub-block

    const int t  = threadIdx.x;
    const int s_ = t >> 8;                    // sub-block 0/1
    const int tl = t & 255;
    const int tx = tl & 15;
    const int ty = tl >> 4;
    float* base = smem + s_ * 8192;

    // triangular decode: tid -> (ri, ci), ri <= ci  (scalar, <=32 iters)
    int rem = blockIdx.x * 2 + s_;
    int ri = 0;
    while (rem >= 32 - ri) { rem -= 32 - ri; ++ri; }
    const int ci = ri + rem;
    const int rowbase = ri * 128;
    const int colbase = ci * 128;

    auto STAGE = [&](int st, int buf) {
        const int c0 = st * 16;
        float* Ab = base + (buf ? 2048 : 0);
        float* Bb = base + 4096 + (buf ? 2048 : 0);
        #pragma unroll
        for (int j = 0; j < 2; ++j) {         // A: 512 float4
            int f = j * 256 + tl;
            int cl = f >> 5, q = f & 31;
            int qi = (q & 24) | ((q - (q >> 3)) & 7);  // inv of swz
            gload16(&xb[(size_t)(c0 + cl) * Nn + rowbase + qi * 4],
                    &Ab[(f & ~63) * 4]);
        }
        #pragma unroll
        for (int j = 0; j < 2; ++j) {         // B: 512 float4
            int f = j * 256 + tl;
            int cl = f >> 5, q = f & 31;
            int qi = (q & 24) | ((q - (q >> 3)) & 7);
            gload16(&xb[(size_t)(c0 + cl) * Nn + colbase + qi * 4],
                    &Bb[(f & ~63) * 4]);
        }
    };

    float acc[8][8];
    #pragma unroll
    for (int i = 0; i < 8; ++i)
        #pragma unroll
        for (int j = 0; j < 8; ++j) acc[i][j] = 0.f;

    const int ra0 = swz(ty * 2), ra1 = swz(ty * 2 + 1);
    const int rb0 = swz(tx * 2), rb1 = swz(tx * 2 + 1);

    STAGE(0, 0);
    for (int s = 0; s < 8; ++s) {
        const int buf = s & 1;
        __syncthreads();          // drains vmcnt -> buf landed; block-wide
        if (s < 7) STAGE(s + 1, buf ^ 1);

        const float4* A4 = (const float4*)(base + (buf ? 2048 : 0));
        const float4* B4 = (const float4*)(base + 4096 + (buf ? 2048 : 0));
        #pragma unroll
        for (int cl = 0; cl < 16; ++cl) {
            float4 a0 = A4[cl * 32 + ra0];
            float4 a1 = A4[cl * 32 + ra1];
            float4 b0 = B4[cl * 32 + rb0];
            float4 b1 = B4[cl * 32 + rb1];
            float av[8] = {a0.x, a0.y, a0.z, a0.w, a1.x, a1.y, a1.z, a1.w};
            float bv[8] = {b0.x, b0.y, b0.z, b0.w, b1.x, b1.y, b1.z, b1.w};
            #pragma unroll
            for (int i = 0; i < 8; ++i)
                #pragma unroll
                for (int j = 0; j < 8; ++j)
                    acc[i][j] = fmaf(av[i], bv[j], acc[i][j]); // c-ascending
        }
    }

    // normal store: G[rowbase+ty*8+i][colbase+tx*8 .. +7]
    #pragma unroll
    for (int i = 0; i < 8; ++i) {
        int row = rowbase + ty * 8 + i;
        float4 o0 = {acc[i][0], acc[i][1], acc[i][2], acc[i][3]};
        float4 o1 = {acc[i][4], acc[i][5], acc[i][6], acc[i][7]};
        float4* dst = (float4*)&G[(size_t)row * Nn + colbase + tx * 8];
        dst[0] = o0;
        dst[1] = o1;
    }

    // transposed store for off-diagonal tiles (bitwise == computing tile
    // (ci,ri): fmaf multiply commutes)
    if (ri != ci) {
        #pragma unroll
        for (int j = 0; j < 8; ++j) {
            int row = colbase + tx * 8 + j;
            float4 o0 = {acc[0][j], acc[1][j], acc[2][j], acc[3][j]};
            float4 o1 = {acc[4][j], acc[5][j], acc[6][j], acc[7][j]};
            float4* dst = (float4*)&G[(size_t)row * Nn + rowbase + ty * 8];
            dst[0] = o0;
            dst[1] = o1;
        }
    }
}

// ---------------------------------------------------------------------------
// K2b v3 (r16-proven): per-row top-9 scan, register-only candidates.
// One block per row; 16 d2 candidates/thread in 4 named float4 regs;
// 9 branchless argmin-pop rounds per wave; wave 0 merges 36 values.
// d2 = fmaf(-2,G,sqr+sqc); diagonal exact 0 -> self always selected.
// ---------------------------------------------------------------------------
__global__ __launch_bounds__(256) void k_scan(
        const float* __restrict__ G, const float* __restrict__ sqb,
        int* __restrict__ idxOut, int b) {
    const int t    = threadIdx.x;
    const int lane = t & 63;
    const int w    = t >> 6;                  // wave 0..3
    const int row  = blockIdx.x;
    const float sqr = sqb[row];

    const float4* G4  = (const float4*)&G[(size_t)row * Nn];
    const float4* sq4 = (const float4*)sqb;

    float4 d0, d1, d2v, d3;
    {
        float4 g, s;
        g = G4[t];        s = sq4[t];
        d0.x = fmaf(-2.f, g.x, sqr + s.x); d0.y = fmaf(-2.f, g.y, sqr + s.y);
        d0.z = fmaf(-2.f, g.z, sqr + s.z); d0.w = fmaf(-2.f, g.w, sqr + s.w);
        g = G4[256 + t];  s = sq4[256 + t];
        d1.x = fmaf(-2.f, g.x, sqr + s.x); d1.y = fmaf(-2.f, g.y, sqr + s.y);
        d1.z = fmaf(-2.f, g.z, sqr + s.z); d1.w = fmaf(-2.f, g.w, sqr + s.w);
        g = G4[512 + t];  s = sq4[512 + t];
        d2v.x = fmaf(-2.f, g.x, sqr + s.x); d2v.y = fmaf(-2.f, g.y, sqr + s.y);
        d2v.z = fmaf(-2.f, g.z, sqr + s.z); d2v.w = fmaf(-2.f, g.w, sqr + s.w);
        g = G4[768 + t];  s = sq4[768 + t];
        d3.x = fmaf(-2.f, g.x, sqr + s.x); d3.y = fmaf(-2.f, g.y, sqr + s.y);
        d3.z = fmaf(-2.f, g.z, sqr + s.z); d3.w = fmaf(-2.f, g.w, sqr + s.w);
    }

    float lv; int ls, lc;
    auto localmin = [&]() {
        float v = d0.x; int s = 0;
        #define MSTEP(val, id) { bool tk = (val) < v; v = tk ? (val) : v; s = tk ? (id) : s; }
        MSTEP(d0.y, 1)  MSTEP(d0.z, 2)  MSTEP(d0.w, 3)
        MSTEP(d1.x, 4)  MSTEP(d1.y, 5)  MSTEP(d1.z, 6)  MSTEP(d1.w, 7)
        MSTEP(d2v.x, 8) MSTEP(d2v.y, 9) MSTEP(d2v.z, 10) MSTEP(d2v.w, 11)
        MSTEP(d3.x, 12) MSTEP(d3.y, 13) MSTEP(d3.z, 14) MSTEP(d3.w, 15)
        #undef MSTEP
        lv = v; ls = s;
        lc = ((((s >> 2) * 256 + t) << 2) | (s & 3));   // global col
    };
    auto maskslot = [&]() {
        d0.x = (ls == 0)  ? INFF : d0.x;  d0.y = (ls == 1)  ? INFF : d0.y;
        d0.z = (ls == 2)  ? INFF : d0.z;  d0.w = (ls == 3)  ? INFF : d0.w;
        d1.x = (ls == 4)  ? INFF : d1.x;  d1.y = (ls == 5)  ? INFF : d1.y;
        d1.z = (ls == 6)  ? INFF : d1.z;  d1.w = (ls == 7)  ? INFF : d1.w;
        d2v.x = (ls == 8) ? INFF : d2v.x; d2v.y = (ls == 9)  ? INFF : d2v.y;
        d2v.z = (ls == 10)? INFF : d2v.z; d2v.w = (ls == 11) ? INFF : d2v.w;
        d3.x = (ls == 12) ? INFF : d3.x;  d3.y = (ls == 13) ? INFF : d3.y;
        d3.z = (ls == 14) ? INFF : d3.z;  d3.w = (ls == 15) ? INFF : d3.w;
    };

    localmin();

    __shared__ float ld[4][9];
    __shared__ int   li[4][9];

    #pragma unroll
    for (int k = 0; k < 9; ++k) {
        float v = lv; int i = lc;
        #pragma unroll
        for (int m = 32; m; m >>= 1) {
            float ov = __shfl_xor(v, m);
            int   oi = __shfl_xor(i, m);
            bool tk = (ov < v) || (ov == v && oi < i);
            v = tk ? ov : v;
            i = tk ? oi : i;
        }
        if (lane == 0) { ld[w][k] = v; li[w][k] = i; }
        if (lc == i) {                        // my candidate won: pop it
            maskslot();
            localmin();
        }
    }
    __syncthreads();

    if (w == 0) {
        float v36 = INFF; int i36 = 0x7fffffff;
        if (lane < 36) {
            int wl = lane / 9, kk = lane - wl * 9;
            v36 = ld[wl][kk];
            i36 = li[wl][kk];
        }
        #pragma unroll
        for (int k = 0; k < 9; ++k) {
            float v = v36; int i = i36;
            #pragma unroll
            for (int m = 32; m; m >>= 1) {
                float ov = __shfl_xor(v, m);
                int   oi = __shfl_xor(i, m);
                bool tk = (ov < v) || (ov == v && oi < i);
                v = tk ? ov : v;
                i = tk ? oi : i;
            }
            if (lane == 0)
                idxOut[((size_t)b * 9 + k) * Nn + row] = i;
            if (i36 == i) v36 = INFF;         // self-mask (cols unique)
        }
    }
}

// ===========================================================================
// FALLBACK PATH (r13, proven): fused gram+top9 + merge, if ws too small.
// ===========================================================================
__global__ __launch_bounds__(256, 1) void k_gram_topk(
        const float* __restrict__ x, const float* __restrict__ sq,
        float* __restrict__ pd, int* __restrict__ pi) {
    __shared__ alignas(16) float As[2][32 * 64];    // 2 x 8KB
    __shared__ alignas(16) float Bs[2][32 * 128];   // 2 x 16KB

    const int t  = threadIdx.x;
    const int tx = t & 15;
    const int ty = t >> 4;
    const int bid = blockIdx.x;               // (b*64 + rg)*8 + oct
    const int b   = bid >> 9;
    const int rg  = (bid >> 3) & 63;
    const int oct = bid & 7;
    const int rowbase = rg * 64;
    const int coloct = oct * 512;
    const float* xb  = x + (size_t)b * Cc * Nn;
    const float* sqb = sq + b * Nn;

    float rown[4];
    #pragma unroll
    for (int i = 0; i < 4; ++i) rown[i] = sqb[rowbase + ty * 4 + i];

    float cd[4][9]; int ci[4][9];
    #pragma unroll
    for (int i = 0; i < 4; ++i)
        #pragma unroll
        for (int p = 0; p < 9; ++p) { cd[i][p] = INFF; ci[i][p] = 0; }

    const int ra  = swz16(ty);
    const int rb0 = swz(tx * 2), rb1 = swz(tx * 2 + 1);

    auto STAGE = [&](int s, int buf) {
        const int c0 = (s & 3) * 32;
        const int colbase = coloct + (s >> 2) * 128;
        float* Ab = &As[buf][0];
        float* Bb = &Bs[buf][0];
        #pragma unroll
        for (int j = 0; j < 2; ++j) {
            int f = j * 256 + t;
            int cl = f >> 4, q = f & 15;
            int qi = (q & 8) | ((q - (q >> 3)) & 7);
            gload16(&xb[(size_t)(c0 + cl) * Nn + rowbase + qi * 4],
                    &Ab[(f & ~63) * 4]);
        }
        #pragma unroll
        for (int j = 0; j < 4; ++j) {
            int f = j * 256 + t;
            int cl = f >> 5, q = f & 31;
            int qi = (q & 24) | ((q - (q >> 3)) & 7);
            gload16(&xb[(size_t)(c0 + cl) * Nn + colbase + qi * 4],
                    &Bb[(f & ~63) * 4]);
        }
    };

    STAGE(0, 0);
    float acc[4][8];
    for (int s = 0; s < 16; ++s) {
        const int buf = s & 1;
        __syncthreads();
        if (s < 15) STAGE(s + 1, buf ^ 1);

        if ((s & 3) == 0) {
            #pragma unroll
            for (int i = 0; i < 4; ++i)
                #pragma unroll
                for (int j = 0; j < 8; ++j) acc[i][j] = 0.f;
        }

        const float4* A4 = (const float4*)&As[buf][0];
        const float4* B4 = (const float4*)&Bs[buf][0];
        #pragma unroll 4
        for (int cl = 0; cl < 32; ++cl) {
            float4 a  = A4[cl * 16 + ra];
            float4 b0 = B4[cl * 32 + rb0];
            float4 b1 = B4[cl * 32 + rb1];
            float av[4] = {a.x, a.y, a.z, a.w};
            float bv[8] = {b0.x, b0.y, b0.z, b0.w, b1.x, b1.y, b1.z, b1.w};
            #pragma unroll
            for (int i = 0; i < 4; ++i)
                #pragma unroll
                for (int j = 0; j < 8; ++j)
                    acc[i][j] = fmaf(av[i], bv[j], acc[i][j]);
        }

        if ((s & 3) == 3) {
            const int colbase = coloct + (s >> 2) * 128;
            float4 cn0 = *(const float4*)&sqb[colbase + tx * 8];
            float4 cn1 = *(const float4*)&sqb[colbase + tx * 8 + 4];
            float cn[8] = {cn0.x, cn0.y, cn0.z, cn0.w,
                           cn1.x, cn1.y, cn1.z, cn1.w};
            #pragma unroll
            for (int i = 0; i < 4; ++i)
                #pragma unroll
                for (int j = 0; j < 8; ++j) {
                    float dd = fmaf(-2.0f, acc[i][j], rown[i] + cn[j]);
                    if (dd < cd[i][8])
                        insert9(cd[i], ci[i], dd, colbase + tx * 8 + j);
                }
        }
    }

    #pragma unroll
    for (int m = 1; m < 16; m <<= 1) {
        #pragma unroll
        for (int i = 0; i < 4; ++i) {
            float od[9]; int oi[9];
            #pragma unroll
            for (int p = 0; p < 9; ++p) {
                od[p] = __shfl_xor(cd[i][p], m);
                oi[p] = __shfl_xor(ci[i][p], m);
            }
            #pragma unroll
            for (int p = 0; p < 9; ++p)
                if (od[p] < cd[i][8]) insert9(cd[i], ci[i], od[p], oi[p]);
        }
    }

    if (tx == 0) {
        #pragma unroll
        for (int i = 0; i < 4; ++i) {
            int n = rowbase + ty * 4 + i;
            #pragma unroll
            for (int k = 0; k < 9; ++k) {
                size_t o = (((size_t)b * 8 + oct) * 9 + k) * Nn + n;
                pd[o] = cd[i][k];
                pi[o] = ci[i][k];
            }
        }
    }
}

__global__ void k_merge(const float* __restrict__ pd, const int* __restrict__ pi,
                        int* __restrict__ idxOut) {
    int id = blockIdx.x * 256 + threadIdx.x;  // 16384
    int b = id >> 12, n = id & (Nn - 1);
    float d0[9]; int i0[9];
    #pragma unroll
    for (int k = 0; k < 9; ++k) {
        size_t o = (((size_t)b * 8 + 0) * 9 + k) * Nn + n;
        d0[k] = pd[o]; i0[k] = pi[o];
    }
    #pragma unroll
    for (int q = 1; q < 8; ++q) {
        #pragma unroll
        for (int k = 0; k < 9; ++k) {
            size_t o = (((size_t)b * 8 + q) * 9 + k) * Nn + n;
            float dv = pd[o]; int iv = pi[o];
            if (dv < d0[8]) insert9(d0, i0, dv, iv);
        }
    }
    #pragma unroll
    for (int k = 0; k < 9; ++k)
        idxOut[((size_t)b * 9 + k) * Nn + n] = i0[k];
}

// ---------------------------------------------------------------------------
// K3: h0[b][c][n] = (1+eps)*x[b][c][n] + sum_k x[b][c][idx[b][k][n]]
// ---------------------------------------------------------------------------
__global__ void k_gather(const float* __restrict__ x, const int* __restrict__ idx,
                         const float* __restrict__ epsp, float* __restrict__ h0) {
    int id = blockIdx.x * 256 + threadIdx.x;          // B*C*N = 2097152
    int n  = id & (Nn - 1);
    int bc = id >> 12;                                // b*C + c
    int b  = bc >> 7;
    const float* xr = x + (size_t)bc * Nn;
    const int* ib = idx + (size_t)b * 9 * Nn + n;
    float s = (1.0f + epsp[0]) * xr[n];
    #pragma unroll
    for (int k = 0; k < 9; ++k) s += xr[ib[(size_t)k * Nn]];
    h0[id] = s;
}

// ---------------------------------------------------------------------------
// K4/K5: out[b][d][n] = act( bias[d] + sum_c W[c][d] * in[b][c][n] )
// ---------------------------------------------------------------------------
template <bool RELU>
__global__ __launch_bounds__(256, 2) void k_mlp(
        const float* __restrict__ in, const float* __restrict__ W,
        const float* __restrict__ bias, float* __restrict__ out) {
    const int t  = threadIdx.x;
    const int td = t & 15;
    const int tn = t >> 4;
    const int bid = blockIdx.x;   // B*2*64 = 512
    const int b = bid >> 7;
    const int dbase = ((bid >> 6) & 1) * 64;
    const int nb = (bid & 63) * 64;

    __shared__ alignas(16) float Ws[128 * 64];
    __shared__ alignas(16) float Hs[128 * 64];

    for (int k = t; k < 128 * 64; k += 256) {
        int i = k & 63; int c = k >> 6;
        int sw = c * 64 + ((((i >> 2) ^ (c & 7)) << 2) | (i & 3));
        Ws[sw] = W[c * 128 + dbase + i];
        Hs[sw] = in[((size_t)b * 128 + c) * Nn + nb + i];
    }
    __syncthreads();

    float acc[4][4];
    #pragma unroll
    for (int dd = 0; dd < 4; ++dd)
        #pragma unroll
        for (int nn = 0; nn < 4; ++nn) acc[dd][nn] = 0.f;

    const float4* W4 = reinterpret_cast<const float4*>(Ws);
    const float4* H4 = reinterpret_cast<const float4*>(Hs);
    for (int c = 0; c < 128; ++c) {
        int cx = c & 7;
        float4 w = W4[c * 16 + (td ^ cx)];
        float4 h = H4[c * 16 + (tn ^ cx)];
        float wf[4] = {w.x, w.y, w.z, w.w};
        float hf[4] = {h.x, h.y, h.z, h.w};
        #pragma unroll
        for (int dd = 0; dd < 4; ++dd)
            #pragma unroll
            for (int nn = 0; nn < 4; ++nn)
                acc[dd][nn] = fmaf(wf[dd], hf[nn], acc[dd][nn]);
    }

    #pragma unroll
    for (int dd = 0; dd < 4; ++dd) {
        int d = dbase + 4 * td + dd;
        float bb = bias[d];
        float4 o;
        o.x = acc[dd][0] + bb; o.y = acc[dd][1] + bb;
        o.z = acc[dd][2] + bb; o.w = acc[dd][3] + bb;
        if (RELU) {
            o.x = fmaxf(o.x, 0.f); o.y = fmaxf(o.y, 0.f);
            o.z = fmaxf(o.z, 0.f); o.w = fmaxf(o.w, 0.f);
        }
        *reinterpret_cast<float4*>(&out[((size_t)b * 128 + d) * Nn + nb + 4 * tn]) = o;
    }
}

// ---------------------------------------------------------------------------
// K6: per-channel batch-norm stats (biased var), 1 block per channel.
// ---------------------------------------------------------------------------
__global__ void k_bnstats(const float* __restrict__ o, const float* __restrict__ gamma,
                          const float* __restrict__ beta, float* __restrict__ scsh) {
    int e = blockIdx.x, t = threadIdx.x;
    float s = 0.f, s2 = 0.f;
    for (int b = 0; b < Bc; ++b) {
        const float* p = o + ((size_t)b * 128 + e) * Nn;
        for (int n = t; n < Nn; n += 256) {
            float v = p[n];
            s += v;
            s2 = fmaf(v, v, s2);
        }
    }
    __shared__ float rs[256], rq[256];
    rs[t] = s; rq[t] = s2;
    __syncthreads();
    for (int off = 128; off > 0; off >>= 1) {
        if (t < off) { rs[t] += rs[t + off]; rq[t] += rq[t + off]; }
        __syncthreads();
    }
    if (t == 0) {
        float mean = rs[0] * (1.0f / 16384.0f);
        float var  = rq[0] * (1.0f / 16384.0f) - mean * mean;
        if (var < 0.f) var = 0.f;
        float sc = gamma[e] * rsqrtf(var + 1e-5f);
        scsh[e] = sc;
        scsh[128 + e] = beta[e] - mean * sc;
    }
}

// ---------------------------------------------------------------------------
// K7: out = relu(scale[e]*o + shift[e] + x), in place on d_out, float4.
// ---------------------------------------------------------------------------
__global__ void k_bnapply(float* __restrict__ o, const float* __restrict__ x,
                          const float* __restrict__ scsh) {
    int id4 = blockIdx.x * 256 + threadIdx.x;         // 524288
    int e = (id4 >> 10) & 127;
    float sc = scsh[e], sh = scsh[128 + e];
    float4 v = reinterpret_cast<const float4*>(o)[id4];
    float4 r = reinterpret_cast<const float4*>(x)[id4];
    float4 w;
    w.x = fmaxf(fmaf(sc, v.x, sh) + r.x, 0.f);
    w.y = fmaxf(fmaf(sc, v.y, sh) + r.y, 0.f);
    w.z = fmaxf(fmaf(sc, v.z, sh) + r.z, 0.f);
    w.w = fmaxf(fmaf(sc, v.w, sh) + r.w, 0.f);
    reinterpret_cast<float4*>(o)[id4] = w;
}

// ---------------------------------------------------------------------------
extern "C" void kernel_launch(void* const* d_in, const int* in_sizes, int n_in,
                              void* d_out, int out_size, void* d_ws, size_t ws_size,
                              hipStream_t stream) {
    const float* x     = (const float*)d_in[0];
    const float* epsp  = (const float*)d_in[1];
    const float* W1    = (const float*)d_in[2];
    const float* b1    = (const float*)d_in[3];
    const float* W2    = (const float*)d_in[4];
    const float* b2    = (const float*)d_in[5];
    const float* gamma = (const float*)d_in[6];
    const float* beta  = (const float*)d_in[7];
    float* out = (float*)d_out;

    // common layout (floats): sq[16384] | idx[147456] | h0[2097152] |
    // h1[2097152] | scsh[256] = 4358400 floats (~16.6MB)
    float* ws   = (float*)d_ws;
    float* sq   = ws;
    int*   idx  = (int*)(ws + 16384);
    float* h0   = ws + 16384 + (size_t)Bc * 9 * Nn;
    float* h1   = h0 + (size_t)Bc * Cc * Nn;
    float* scsh = h1 + (size_t)Bc * Cc * Nn;
    float* G    = ws + 4358400;               // [4096][4096] = 67.1MB

    const size_t need = 4358400ull * 4 + (size_t)Nn * Nn * 4;  // ~84.5MB

    k_sq <<<64, 256, 0, stream>>>(x, sq);

    if (ws_size >= need) {
        // two-pass: per batch, symmetric GEMM (264 x 512-thr blocks, 2 tiles
        // each, dual store) -> G, then per-row register-only scan.
        for (int b = 0; b < Bc; ++b) {
            k_gemm2<<<264,  512, 0, stream>>>(x + (size_t)b * Cc * Nn, G);
            k_scan <<<4096, 256, 0, stream>>>(G, sq + (size_t)b * Nn, idx, b);
        }
    } else {
        // fallback: r13 fused path; pd aliases h0, pi aliases h1
        float* pd = h0;
        int*   pi = (int*)h1;
        k_gram_topk<<<2048, 256, 0, stream>>>(x, sq, pd, pi);
        k_merge    <<<64,   256, 0, stream>>>(pd, pi, idx);
    }

    k_gather    <<<8192, 256, 0, stream>>>(x, idx, epsp, h0);
    k_mlp<true> <<<512,  256, 0, stream>>>(h0, W1, b1, h1);
    k_mlp<false><<<512,  256, 0, stream>>>(h1, W2, b2, out);
    k_bnstats   <<<128,  256, 0, stream>>>(out, gamma, beta, scsh);
    k_bnapply   <<<2048, 256, 0, stream>>>(out, x, scsh);
}

// Round 23
// 412.903 us; speedup vs baseline: 3.7418x; 1.1631x over previous
//
#include <hip/hip_runtime.h>
#include <hip/hip_bf16.h>

#define Bc 4
#define Cc 128
#define Nn 4096
#define INFF 3.4e38f

// ---------------------------------------------------------------------------
// K1: sq[b*N + n] = sum_c x[b][c][n]^2, sequential ascending FMA chain.
// MUST match the Gram accumulation chain bitwise so self-distance == 0.
// ---------------------------------------------------------------------------
__global__ void k_sq(const float* __restrict__ x, float* __restrict__ sq) {
    int id = blockIdx.x * 256 + threadIdx.x;          // 16384 total
    int b = id >> 12, n = id & (Nn - 1);
    const float* xb = x + (size_t)b * Cc * Nn + n;
    float a = 0.f;
    #pragma unroll 8
    for (int c = 0; c < Cc; ++c) {
        float v = xb[(size_t)c * Nn];
        a = fmaf(v, v, a);
    }
    sq[id] = a;
}

// ---------------------------------------------------------------------------
// sorted-ascending top-9 insert (fallback path only).
// ---------------------------------------------------------------------------
__device__ __forceinline__ void insert9(float (&d)[9], int (&ix)[9], float nd, int ni) {
    float cx = nd; int cI = ni;
    #pragma unroll
    for (int p = 0; p < 9; ++p) {
        bool lt = cx < d[p];
        float td = d[p]; int ti = ix[p];
        if (lt) { d[p] = cx; ix[p] = cI; cx = td; cI = ti; }
    }
}

// Chunk swizzles (rotate within each 8-chunk run by run index) + inverses.
__device__ __forceinline__ int swz(int q)    { return (q & 24) | ((q + (q >> 3)) & 7); }
__device__ __forceinline__ int swz16(int q)  { return (q & 8)  | ((q + (q >> 3)) & 7); }

// global -> LDS direct 16B async copy
__device__ __forceinline__ void gload16(const float* g, float* l) {
    __builtin_amdgcn_global_load_lds(
        (const __attribute__((address_space(1))) void*)g,
        (__attribute__((address_space(3))) void*)l, 16, 0, 0);
}

// ===========================================================================
// TWO-PASS PATH (r18 skeleton, proven 413us). r22 evidence: occupancy tracks
// GRID SIZE (528->12%, 1024->18%, 2048->23-30%); 512-thr blocks regressed.
// This round: batch all 4 batches' tiles into ONE dispatch (grid 2112) with
// 4 G buffers, and all scans into one (grid 16384). Kernel math unchanged.
// ===========================================================================

// ---------------------------------------------------------------------------
// K2a (r18 core + batch decode): b = bid/528, then triangular decode.
// 256 thr, 32KB dbuf LDS, gload_lds staging, chain c = st*16+cl ascending
// == k_sq bitwise -> diagonal d2 exactly 0. Off-diag tiles dual-stored
// (fmaf multiply commutes -> bitwise symmetric).
// Per-batch tier: launch grid 528 with offset pointers (b decodes to 0).
// ---------------------------------------------------------------------------
__global__ __launch_bounds__(256, 1) void k_gemm_all(
        const float* __restrict__ x, float* __restrict__ Gall) {
    __shared__ alignas(16) float smem[8192];   // 32KB

    const int t  = threadIdx.x;
    const int tx = t & 15;
    const int ty = t >> 4;

    const int b = blockIdx.x / 528;
    int rem = blockIdx.x - b * 528;
    int ri = 0;
    while (rem >= 32 - ri) { rem -= 32 - ri; ++ri; }   // <=32 iters, scalar
    const int ci = ri + rem;
    const int rowbase = ri * 128;
    const int colbase = ci * 128;

    const float* xb = x + (size_t)b * Cc * Nn;
    float* G = Gall + (size_t)b * Nn * Nn;

    auto STAGE = [&](int st, int buf) {
        const int c0 = st * 16;
        float* Ab = smem + (buf ? 2048 : 0);
        float* Bb = smem + 4096 + (buf ? 2048 : 0);
        #pragma unroll
        for (int j = 0; j < 2; ++j) {         // A: 512 float4
            int f = j * 256 + t;
            int cl = f >> 5, q = f & 31;
            int qi = (q & 24) | ((q - (q >> 3)) & 7);  // inv of swz
            gload16(&xb[(size_t)(c0 + cl) * Nn + rowbase + qi * 4],
                    &Ab[(f & ~63) * 4]);
        }
        #pragma unroll
        for (int j = 0; j < 2; ++j) {         // B: 512 float4
            int f = j * 256 + t;
            int cl = f >> 5, q = f & 31;
            int qi = (q & 24) | ((q - (q >> 3)) & 7);
            gload16(&xb[(size_t)(c0 + cl) * Nn + colbase + qi * 4],
                    &Bb[(f & ~63) * 4]);
        }
    };

    float acc[8][8];
    #pragma unroll
    for (int i = 0; i < 8; ++i)
        #pragma unroll
        for (int j = 0; j < 8; ++j) acc[i][j] = 0.f;

    const int ra0 = swz(ty * 2), ra1 = swz(ty * 2 + 1);
    const int rb0 = swz(tx * 2), rb1 = swz(tx * 2 + 1);

    STAGE(0, 0);
    for (int s = 0; s < 8; ++s) {
        const int buf = s & 1;
        __syncthreads();          // drains vmcnt -> buf landed; syncs block
        if (s < 7) STAGE(s + 1, buf ^ 1);

        const float4* A4 = (const float4*)(smem + (buf ? 2048 : 0));
        const float4* B4 = (const float4*)(smem + 4096 + (buf ? 2048 : 0));
        #pragma unroll
        for (int cl = 0; cl < 16; ++cl) {
            float4 a0 = A4[cl * 32 + ra0];
            float4 a1 = A4[cl * 32 + ra1];
            float4 b0 = B4[cl * 32 + rb0];
            float4 b1 = B4[cl * 32 + rb1];
            float av[8] = {a0.x, a0.y, a0.z, a0.w, a1.x, a1.y, a1.z, a1.w};
            float bv[8] = {b0.x, b0.y, b0.z, b0.w, b1.x, b1.y, b1.z, b1.w};
            #pragma unroll
            for (int i = 0; i < 8; ++i)
                #pragma unroll
                for (int j = 0; j < 8; ++j)
                    acc[i][j] = fmaf(av[i], bv[j], acc[i][j]); // c-ascending
        }
    }

    // normal store: G[rowbase+ty*8+i][colbase+tx*8 .. +7]
    #pragma unroll
    for (int i = 0; i < 8; ++i) {
        int row = rowbase + ty * 8 + i;
        float4 o0 = {acc[i][0], acc[i][1], acc[i][2], acc[i][3]};
        float4 o1 = {acc[i][4], acc[i][5], acc[i][6], acc[i][7]};
        float4* dst = (float4*)&G[(size_t)row * Nn + colbase + tx * 8];
        dst[0] = o0;
        dst[1] = o1;
    }

    // transposed store for off-diagonal tiles (bitwise == computing tile
    // (ci,ri): fmaf multiply commutes)
    if (ri != ci) {
        #pragma unroll
        for (int j = 0; j < 8; ++j) {
            int row = colbase + tx * 8 + j;
            float4 o0 = {acc[0][j], acc[1][j], acc[2][j], acc[3][j]};
            float4 o1 = {acc[4][j], acc[5][j], acc[6][j], acc[7][j]};
            float4* dst = (float4*)&G[(size_t)row * Nn + rowbase + ty * 8];
            dst[0] = o0;
            dst[1] = o1;
        }
    }
}

// ---------------------------------------------------------------------------
// K2b (r16-proven scan + batch decode): bb = bid>>12 (0 for per-batch tier).
// One block per row; 16 d2 candidates/thread in 4 named float4 regs;
// 9 branchless argmin-pop rounds per wave; wave 0 merges 36 values.
// d2 = fmaf(-2,G,sqr+sqc); diagonal exact 0 -> self always selected.
// ---------------------------------------------------------------------------
__global__ __launch_bounds__(256) void k_scan_all(
        const float* __restrict__ Gall, const float* __restrict__ sq,
        int* __restrict__ idxOut, int bbase) {
    const int t    = threadIdx.x;
    const int lane = t & 63;
    const int w    = t >> 6;                  // wave 0..3
    const int bb   = blockIdx.x >> 12;        // local batch
    const int row  = blockIdx.x & (Nn - 1);
    const int b    = bbase + bb;
    const float* sqb = sq + (size_t)b * Nn;
    const float sqr = sqb[row];

    const float4* G4  = (const float4*)(Gall + (size_t)bb * Nn * Nn + (size_t)row * Nn);
    const float4* sq4 = (const float4*)sqb;

    float4 d0, d1, d2v, d3;
    {
        float4 g, s;
        g = G4[t];        s = sq4[t];
        d0.x = fmaf(-2.f, g.x, sqr + s.x); d0.y = fmaf(-2.f, g.y, sqr + s.y);
        d0.z = fmaf(-2.f, g.z, sqr + s.z); d0.w = fmaf(-2.f, g.w, sqr + s.w);
        g = G4[256 + t];  s = sq4[256 + t];
        d1.x = fmaf(-2.f, g.x, sqr + s.x); d1.y = fmaf(-2.f, g.y, sqr + s.y);
        d1.z = fmaf(-2.f, g.z, sqr + s.z); d1.w = fmaf(-2.f, g.w, sqr + s.w);
        g = G4[512 + t];  s = sq4[512 + t];
        d2v.x = fmaf(-2.f, g.x, sqr + s.x); d2v.y = fmaf(-2.f, g.y, sqr + s.y);
        d2v.z = fmaf(-2.f, g.z, sqr + s.z); d2v.w = fmaf(-2.f, g.w, sqr + s.w);
        g = G4[768 + t];  s = sq4[768 + t];
        d3.x = fmaf(-2.f, g.x, sqr + s.x); d3.y = fmaf(-2.f, g.y, sqr + s.y);
        d3.z = fmaf(-2.f, g.z, sqr + s.z); d3.w = fmaf(-2.f, g.w, sqr + s.w);
    }

    float lv; int ls, lc;
    auto localmin = [&]() {
        float v = d0.x; int s = 0;
        #define MSTEP(val, id) { bool tk = (val) < v; v = tk ? (val) : v; s = tk ? (id) : s; }
        MSTEP(d0.y, 1)  MSTEP(d0.z, 2)  MSTEP(d0.w, 3)
        MSTEP(d1.x, 4)  MSTEP(d1.y, 5)  MSTEP(d1.z, 6)  MSTEP(d1.w, 7)
        MSTEP(d2v.x, 8) MSTEP(d2v.y, 9) MSTEP(d2v.z, 10) MSTEP(d2v.w, 11)
        MSTEP(d3.x, 12) MSTEP(d3.y, 13) MSTEP(d3.z, 14) MSTEP(d3.w, 15)
        #undef MSTEP
        lv = v; ls = s;
        lc = ((((s >> 2) * 256 + t) << 2) | (s & 3));   // global col
    };
    auto maskslot = [&]() {
        d0.x = (ls == 0)  ? INFF : d0.x;  d0.y = (ls == 1)  ? INFF : d0.y;
        d0.z = (ls == 2)  ? INFF : d0.z;  d0.w = (ls == 3)  ? INFF : d0.w;
        d1.x = (ls == 4)  ? INFF : d1.x;  d1.y = (ls == 5)  ? INFF : d1.y;
        d1.z = (ls == 6)  ? INFF : d1.z;  d1.w = (ls == 7)  ? INFF : d1.w;
        d2v.x = (ls == 8) ? INFF : d2v.x; d2v.y = (ls == 9)  ? INFF : d2v.y;
        d2v.z = (ls == 10)? INFF : d2v.z; d2v.w = (ls == 11) ? INFF : d2v.w;
        d3.x = (ls == 12) ? INFF : d3.x;  d3.y = (ls == 13) ? INFF : d3.y;
        d3.z = (ls == 14) ? INFF : d3.z;  d3.w = (ls == 15) ? INFF : d3.w;
    };

    localmin();

    __shared__ float ld[4][9];
    __shared__ int   li[4][9];

    #pragma unroll
    for (int k = 0; k < 9; ++k) {
        float v = lv; int i = lc;
        #pragma unroll
        for (int m = 32; m; m >>= 1) {
            float ov = __shfl_xor(v, m);
            int   oi = __shfl_xor(i, m);
            bool tk = (ov < v) || (ov == v && oi < i);
            v = tk ? ov : v;
            i = tk ? oi : i;
        }
        if (lane == 0) { ld[w][k] = v; li[w][k] = i; }
        if (lc == i) {                        // my candidate won: pop it
            maskslot();
            localmin();
        }
    }
    __syncthreads();

    if (w == 0) {
        float v36 = INFF; int i36 = 0x7fffffff;
        if (lane < 36) {
            int wl = lane / 9, kk = lane - wl * 9;
            v36 = ld[wl][kk];
            i36 = li[wl][kk];
        }
        #pragma unroll
        for (int k = 0; k < 9; ++k) {
            float v = v36; int i = i36;
            #pragma unroll
            for (int m = 32; m; m >>= 1) {
                float ov = __shfl_xor(v, m);
                int   oi = __shfl_xor(i, m);
                bool tk = (ov < v) || (ov == v && oi < i);
                v = tk ? ov : v;
                i = tk ? oi : i;
            }
            if (lane == 0)
                idxOut[((size_t)b * 9 + k) * Nn + row] = i;
            if (i36 == i) v36 = INFF;         // self-mask (cols unique)
        }
    }
}

// ===========================================================================
// FALLBACK PATH (r13, proven): fused gram+top9 + merge, if ws too small.
// ===========================================================================
__global__ __launch_bounds__(256, 1) void k_gram_topk(
        const float* __restrict__ x, const float* __restrict__ sq,
        float* __restrict__ pd, int* __restrict__ pi) {
    __shared__ alignas(16) float As[2][32 * 64];    // 2 x 8KB
    __shared__ alignas(16) float Bs[2][32 * 128];   // 2 x 16KB

    const int t  = threadIdx.x;
    const int tx = t & 15;
    const int ty = t >> 4;
    const int bid = blockIdx.x;               // (b*64 + rg)*8 + oct
    const int b   = bid >> 9;
    const int rg  = (bid >> 3) & 63;
    const int oct = bid & 7;
    const int rowbase = rg * 64;
    const int coloct = oct * 512;
    const float* xb  = x + (size_t)b * Cc * Nn;
    const float* sqb = sq + b * Nn;

    float rown[4];
    #pragma unroll
    for (int i = 0; i < 4; ++i) rown[i] = sqb[rowbase + ty * 4 + i];

    float cd[4][9]; int ci[4][9];
    #pragma unroll
    for (int i = 0; i < 4; ++i)
        #pragma unroll
        for (int p = 0; p < 9; ++p) { cd[i][p] = INFF; ci[i][p] = 0; }

    const int ra  = swz16(ty);
    const int rb0 = swz(tx * 2), rb1 = swz(tx * 2 + 1);

    auto STAGE = [&](int s, int buf) {
        const int c0 = (s & 3) * 32;
        const int colbase = coloct + (s >> 2) * 128;
        float* Ab = &As[buf][0];
        float* Bb = &Bs[buf][0];
        #pragma unroll
        for (int j = 0; j < 2; ++j) {
            int f = j * 256 + t;
            int cl = f >> 4, q = f & 15;
            int qi = (q & 8) | ((q - (q >> 3)) & 7);
            gload16(&xb[(size_t)(c0 + cl) * Nn + rowbase + qi * 4],
                    &Ab[(f & ~63) * 4]);
        }
        #pragma unroll
        for (int j = 0; j < 4; ++j) {
            int f = j * 256 + t;
            int cl = f >> 5, q = f & 31;
            int qi = (q & 24) | ((q - (q >> 3)) & 7);
            gload16(&xb[(size_t)(c0 + cl) * Nn + colbase + qi * 4],
                    &Bb[(f & ~63) * 4]);
        }
    };

    STAGE(0, 0);
    float acc[4][8];
    for (int s = 0; s < 16; ++s) {
        const int buf = s & 1;
        __syncthreads();
        if (s < 15) STAGE(s + 1, buf ^ 1);

        if ((s & 3) == 0) {
            #pragma unroll
            for (int i = 0; i < 4; ++i)
                #pragma unroll
                for (int j = 0; j < 8; ++j) acc[i][j] = 0.f;
        }

        const float4* A4 = (const float4*)&As[buf][0];
        const float4* B4 = (const float4*)&Bs[buf][0];
        #pragma unroll 4
        for (int cl = 0; cl < 32; ++cl) {
            float4 a  = A4[cl * 16 + ra];
            float4 b0 = B4[cl * 32 + rb0];
            float4 b1 = B4[cl * 32 + rb1];
            float av[4] = {a.x, a.y, a.z, a.w};
            float bv[8] = {b0.x, b0.y, b0.z, b0.w, b1.x, b1.y, b1.z, b1.w};
            #pragma unroll
            for (int i = 0; i < 4; ++i)
                #pragma unroll
                for (int j = 0; j < 8; ++j)
                    acc[i][j] = fmaf(av[i], bv[j], acc[i][j]);
        }

        if ((s & 3) == 3) {
            const int colbase = coloct + (s >> 2) * 128;
            float4 cn0 = *(const float4*)&sqb[colbase + tx * 8];
            float4 cn1 = *(const float4*)&sqb[colbase + tx * 8 + 4];
            float cn[8] = {cn0.x, cn0.y, cn0.z, cn0.w,
                           cn1.x, cn1.y, cn1.z, cn1.w};
            #pragma unroll
            for (int i = 0; i < 4; ++i)
                #pragma unroll
                for (int j = 0; j < 8; ++j) {
                    float dd = fmaf(-2.0f, acc[i][j], rown[i] + cn[j]);
                    if (dd < cd[i][8])
                        insert9(cd[i], ci[i], dd, colbase + tx * 8 + j);
                }
        }
    }

    #pragma unroll
    for (int m = 1; m < 16; m <<= 1) {
        #pragma unroll
        for (int i = 0; i < 4; ++i) {
            float od[9]; int oi[9];
            #pragma unroll
            for (int p = 0; p < 9; ++p) {
                od[p] = __shfl_xor(cd[i][p], m);
                oi[p] = __shfl_xor(ci[i][p], m);
            }
            #pragma unroll
            for (int p = 0; p < 9; ++p)
                if (od[p] < cd[i][8]) insert9(cd[i], ci[i], od[p], oi[p]);
        }
    }

    if (tx == 0) {
        #pragma unroll
        for (int i = 0; i < 4; ++i) {
            int n = rowbase + ty * 4 + i;
            #pragma unroll
            for (int k = 0; k < 9; ++k) {
                size_t o = (((size_t)b * 8 + oct) * 9 + k) * Nn + n;
                pd[o] = cd[i][k];
                pi[o] = ci[i][k];
            }
        }
    }
}

__global__ void k_merge(const float* __restrict__ pd, const int* __restrict__ pi,
                        int* __restrict__ idxOut) {
    int id = blockIdx.x * 256 + threadIdx.x;  // 16384
    int b = id >> 12, n = id & (Nn - 1);
    float d0[9]; int i0[9];
    #pragma unroll
    for (int k = 0; k < 9; ++k) {
        size_t o = (((size_t)b * 8 + 0) * 9 + k) * Nn + n;
        d0[k] = pd[o]; i0[k] = pi[o];
    }
    #pragma unroll
    for (int q = 1; q < 8; ++q) {
        #pragma unroll
        for (int k = 0; k < 9; ++k) {
            size_t o = (((size_t)b * 8 + q) * 9 + k) * Nn + n;
            float dv = pd[o]; int iv = pi[o];
            if (dv < d0[8]) insert9(d0, i0, dv, iv);
        }
    }
    #pragma unroll
    for (int k = 0; k < 9; ++k)
        idxOut[((size_t)b * 9 + k) * Nn + n] = i0[k];
}

// ---------------------------------------------------------------------------
// K3: h0[b][c][n] = (1+eps)*x[b][c][n] + sum_k x[b][c][idx[b][k][n]]
// ---------------------------------------------------------------------------
__global__ void k_gather(const float* __restrict__ x, const int* __restrict__ idx,
                         const float* __restrict__ epsp, float* __restrict__ h0) {
    int id = blockIdx.x * 256 + threadIdx.x;          // B*C*N = 2097152
    int n  = id & (Nn - 1);
    int bc = id >> 12;                                // b*C + c
    int b  = bc >> 7;
    const float* xr = x + (size_t)bc * Nn;
    const int* ib = idx + (size_t)b * 9 * Nn + n;
    float s = (1.0f + epsp[0]) * xr[n];
    #pragma unroll
    for (int k = 0; k < 9; ++k) s += xr[ib[(size_t)k * Nn]];
    h0[id] = s;
}

// ---------------------------------------------------------------------------
// K4/K5: out[b][d][n] = act( bias[d] + sum_c W[c][d] * in[b][c][n] )
// ---------------------------------------------------------------------------
template <bool RELU>
__global__ __launch_bounds__(256, 2) void k_mlp(
        const float* __restrict__ in, const float* __restrict__ W,
        const float* __restrict__ bias, float* __restrict__ out) {
    const int t  = threadIdx.x;
    const int td = t & 15;
    const int tn = t >> 4;
    const int bid = blockIdx.x;   // B*2*64 = 512
    const int b = bid >> 7;
    const int dbase = ((bid >> 6) & 1) * 64;
    const int nb = (bid & 63) * 64;

    __shared__ alignas(16) float Ws[128 * 64];
    __shared__ alignas(16) float Hs[128 * 64];

    for (int k = t; k < 128 * 64; k += 256) {
        int i = k & 63; int c = k >> 6;
        int sw = c * 64 + ((((i >> 2) ^ (c & 7)) << 2) | (i & 3));
        Ws[sw] = W[c * 128 + dbase + i];
        Hs[sw] = in[((size_t)b * 128 + c) * Nn + nb + i];
    }
    __syncthreads();

    float acc[4][4];
    #pragma unroll
    for (int dd = 0; dd < 4; ++dd)
        #pragma unroll
        for (int nn = 0; nn < 4; ++nn) acc[dd][nn] = 0.f;

    const float4* W4 = reinterpret_cast<const float4*>(Ws);
    const float4* H4 = reinterpret_cast<const float4*>(Hs);
    for (int c = 0; c < 128; ++c) {
        int cx = c & 7;
        float4 w = W4[c * 16 + (td ^ cx)];
        float4 h = H4[c * 16 + (tn ^ cx)];
        float wf[4] = {w.x, w.y, w.z, w.w};
        float hf[4] = {h.x, h.y, h.z, h.w};
        #pragma unroll
        for (int dd = 0; dd < 4; ++dd)
            #pragma unroll
            for (int nn = 0; nn < 4; ++nn)
                acc[dd][nn] = fmaf(wf[dd], hf[nn], acc[dd][nn]);
    }

    #pragma unroll
    for (int dd = 0; dd < 4; ++dd) {
        int d = dbase + 4 * td + dd;
        float bb = bias[d];
        float4 o;
        o.x = acc[dd][0] + bb; o.y = acc[dd][1] + bb;
        o.z = acc[dd][2] + bb; o.w = acc[dd][3] + bb;
        if (RELU) {
            o.x = fmaxf(o.x, 0.f); o.y = fmaxf(o.y, 0.f);
            o.z = fmaxf(o.z, 0.f); o.w = fmaxf(o.w, 0.f);
        }
        *reinterpret_cast<float4*>(&out[((size_t)b * 128 + d) * Nn + nb + 4 * tn]) = o;
    }
}

// ---------------------------------------------------------------------------
// K6: per-channel batch-norm stats (biased var), 1 block per channel.
// ---------------------------------------------------------------------------
__global__ void k_bnstats(const float* __restrict__ o, const float* __restrict__ gamma,
                          const float* __restrict__ beta, float* __restrict__ scsh) {
    int e = blockIdx.x, t = threadIdx.x;
    float s = 0.f, s2 = 0.f;
    for (int b = 0; b < Bc; ++b) {
        const float* p = o + ((size_t)b * 128 + e) * Nn;
        for (int n = t; n < Nn; n += 256) {
            float v = p[n];
            s += v;
            s2 = fmaf(v, v, s2);
        }
    }
    __shared__ float rs[256], rq[256];
    rs[t] = s; rq[t] = s2;
    __syncthreads();
    for (int off = 128; off > 0; off >>= 1) {
        if (t < off) { rs[t] += rs[t + off]; rq[t] += rq[t + off]; }
        __syncthreads();
    }
    if (t == 0) {
        float mean = rs[0] * (1.0f / 16384.0f);
        float var  = rq[0] * (1.0f / 16384.0f) - mean * mean;
        if (var < 0.f) var = 0.f;
        float sc = gamma[e] * rsqrtf(var + 1e-5f);
        scsh[e] = sc;
        scsh[128 + e] = beta[e] - mean * sc;
    }
}

// ---------------------------------------------------------------------------
// K7: out = relu(scale[e]*o + shift[e] + x), in place on d_out, float4.
// ---------------------------------------------------------------------------
__global__ void k_bnapply(float* __restrict__ o, const float* __restrict__ x,
                          const float* __restrict__ scsh) {
    int id4 = blockIdx.x * 256 + threadIdx.x;         // 524288
    int e = (id4 >> 10) & 127;
    float sc = scsh[e], sh = scsh[128 + e];
    float4 v = reinterpret_cast<const float4*>(o)[id4];
    float4 r = reinterpret_cast<const float4*>(x)[id4];
    float4 w;
    w.x = fmaxf(fmaf(sc, v.x, sh) + r.x, 0.f);
    w.y = fmaxf(fmaf(sc, v.y, sh) + r.y, 0.f);
    w.z = fmaxf(fmaf(sc, v.z, sh) + r.z, 0.f);
    w.w = fmaxf(fmaf(sc, v.w, sh) + r.w, 0.f);
    reinterpret_cast<float4*>(o)[id4] = w;
}

// ---------------------------------------------------------------------------
extern "C" void kernel_launch(void* const* d_in, const int* in_sizes, int n_in,
                              void* d_out, int out_size, void* d_ws, size_t ws_size,
                              hipStream_t stream) {
    const float* x     = (const float*)d_in[0];
    const float* epsp  = (const float*)d_in[1];
    const float* W1    = (const float*)d_in[2];
    const float* b1    = (const float*)d_in[3];
    const float* W2    = (const float*)d_in[4];
    const float* b2    = (const float*)d_in[5];
    const float* gamma = (const float*)d_in[6];
    const float* beta  = (const float*)d_in[7];
    float* out = (float*)d_out;

    // common layout (floats): sq[16384] | idx[147456] | h0[2097152] |
    // h1[2097152] | scsh[256] = 4358400 floats (~16.6MB)
    float* ws   = (float*)d_ws;
    float* sq   = ws;
    int*   idx  = (int*)(ws + 16384);
    float* h0   = ws + 16384 + (size_t)Bc * 9 * Nn;
    float* h1   = h0 + (size_t)Bc * Cc * Nn;
    float* scsh = h1 + (size_t)Bc * Cc * Nn;
    float* G    = ws + 4358400;               // 1 or 4 x [4096][4096]

    const size_t base  = 4358400ull * 4;
    const size_t gsz   = (size_t)Nn * Nn * 4;            // 67.1MB
    const size_t need4 = base + 4 * gsz;                 // ~285MB
    const size_t need1 = base + gsz;                     // ~84.5MB

    k_sq <<<64, 256, 0, stream>>>(x, sq);

    if (ws_size >= need4) {
        // fully batched: one gemm dispatch (2112 blocks -> 2-3 blocks/CU per
        // the measured grid/occupancy curve), one scan dispatch (16384).
        k_gemm_all<<<2112,  256, 0, stream>>>(x, G);
        k_scan_all<<<16384, 256, 0, stream>>>(G, sq, idx, 0);
    } else if (ws_size >= need1) {
        // r18 per-batch tier (proven 413us): same kernels, offset pointers.
        for (int b = 0; b < Bc; ++b) {
            k_gemm_all<<<528,  256, 0, stream>>>(x + (size_t)b * Cc * Nn, G);
            k_scan_all<<<4096, 256, 0, stream>>>(G, sq, idx, b);
        }
    } else {
        // fused fallback (r13, proven): pd aliases h0, pi aliases h1
        float* pd = h0;
        int*   pi = (int*)h1;
        k_gram_topk<<<2048, 256, 0, stream>>>(x, sq, pd, pi);
        k_merge    <<<64,   256, 0, stream>>>(pd, pi, idx);
    }

    k_gather    <<<8192, 256, 0, stream>>>(x, idx, epsp, h0);
    k_mlp<true> <<<512,  256, 0, stream>>>(h0, W1, b1, h1);
    k_mlp<false><<<512,  256, 0, stream>>>(h1, W2, b2, out);
    k_bnstats   <<<128,  256, 0, stream>>>(out, gamma, beta, scsh);
    k_bnapply   <<<2048, 256, 0, stream>>>(out, x, scsh);
}

// Round 24
// 351.427 us; speedup vs baseline: 4.3964x; 1.1749x over previous
//
#include <hip/hip_runtime.h>
#include <hip/hip_bf16.h>

#define Bc 4
#define Cc 128
#define Nn 4096
#define INFF 3.4e38f

// ---------------------------------------------------------------------------
// K1: sq[b*N + n] = sum_c x[b][c][n]^2, sequential ascending FMA chain.
// MUST match the Gram accumulation chain bitwise so self-distance == 0.
// ---------------------------------------------------------------------------
__global__ void k_sq(const float* __restrict__ x, float* __restrict__ sq) {
    int id = blockIdx.x * 256 + threadIdx.x;          // 16384 total
    int b = id >> 12, n = id & (Nn - 1);
    const float* xb = x + (size_t)b * Cc * Nn + n;
    float a = 0.f;
    #pragma unroll 8
    for (int c = 0; c < Cc; ++c) {
        float v = xb[(size_t)c * Nn];
        a = fmaf(v, v, a);
    }
    sq[id] = a;
}

// ---------------------------------------------------------------------------
// sorted-ascending top-9 insert (fallback path only).
// ---------------------------------------------------------------------------
__device__ __forceinline__ void insert9(float (&d)[9], int (&ix)[9], float nd, int ni) {
    float cx = nd; int cI = ni;
    #pragma unroll
    for (int p = 0; p < 9; ++p) {
        bool lt = cx < d[p];
        float td = d[p]; int ti = ix[p];
        if (lt) { d[p] = cx; ix[p] = cI; cx = td; cI = ti; }
    }
}

// Chunk swizzles (rotate within each 8-chunk run by run index) + inverses.
__device__ __forceinline__ int swz(int q)    { return (q & 24) | ((q + (q >> 3)) & 7); }
__device__ __forceinline__ int swz16(int q)  { return (q & 8)  | ((q + (q >> 3)) & 7); }

// global -> LDS direct 16B async copy
__device__ __forceinline__ void gload16(const float* g, float* l) {
    __builtin_amdgcn_global_load_lds(
        (const __attribute__((address_space(1))) void*)g,
        (__attribute__((address_space(3))) void*)l, 16, 0, 0);
}

// ===========================================================================
// TWO-PASS PATH (r18 skeleton). r23 learned: 84.5MB <= ws < 285MB, so the
// 4-batch batched tier never ran. This round adds a 2-batch tier (2 G
// buffers, ~151MB): two gemm dispatches of grid 1056 + two scans of 8192,
// exploiting the measured occupancy-vs-grid curve (528->14%, 1024->18%,
// 2048->23-30%). Kernel bodies unchanged from the r23-passing run.
// ===========================================================================

// ---------------------------------------------------------------------------
// K2a (proven): b = bid/528, then triangular decode. 256 thr, 32KB dbuf
// LDS, gload_lds staging, chain c = st*16+cl ascending == k_sq bitwise ->
// diagonal d2 exactly 0. Off-diag tiles dual-stored (fmaf multiply
// commutes -> bitwise symmetric).
// ---------------------------------------------------------------------------
__global__ __launch_bounds__(256, 1) void k_gemm_all(
        const float* __restrict__ x, float* __restrict__ Gall) {
    __shared__ alignas(16) float smem[8192];   // 32KB

    const int t  = threadIdx.x;
    const int tx = t & 15;
    const int ty = t >> 4;

    const int b = blockIdx.x / 528;
    int rem = blockIdx.x - b * 528;
    int ri = 0;
    while (rem >= 32 - ri) { rem -= 32 - ri; ++ri; }   // <=32 iters, scalar
    const int ci = ri + rem;
    const int rowbase = ri * 128;
    const int colbase = ci * 128;

    const float* xb = x + (size_t)b * Cc * Nn;
    float* G = Gall + (size_t)b * Nn * Nn;

    auto STAGE = [&](int st, int buf) {
        const int c0 = st * 16;
        float* Ab = smem + (buf ? 2048 : 0);
        float* Bb = smem + 4096 + (buf ? 2048 : 0);
        #pragma unroll
        for (int j = 0; j < 2; ++j) {         // A: 512 float4
            int f = j * 256 + t;
            int cl = f >> 5, q = f & 31;
            int qi = (q & 24) | ((q - (q >> 3)) & 7);  // inv of swz
            gload16(&xb[(size_t)(c0 + cl) * Nn + rowbase + qi * 4],
                    &Ab[(f & ~63) * 4]);
        }
        #pragma unroll
        for (int j = 0; j < 2; ++j) {         // B: 512 float4
            int f = j * 256 + t;
            int cl = f >> 5, q = f & 31;
            int qi = (q & 24) | ((q - (q >> 3)) & 7);
            gload16(&xb[(size_t)(c0 + cl) * Nn + colbase + qi * 4],
                    &Bb[(f & ~63) * 4]);
        }
    };

    float acc[8][8];
    #pragma unroll
    for (int i = 0; i < 8; ++i)
        #pragma unroll
        for (int j = 0; j < 8; ++j) acc[i][j] = 0.f;

    const int ra0 = swz(ty * 2), ra1 = swz(ty * 2 + 1);
    const int rb0 = swz(tx * 2), rb1 = swz(tx * 2 + 1);

    STAGE(0, 0);
    for (int s = 0; s < 8; ++s) {
        const int buf = s & 1;
        __syncthreads();          // drains vmcnt -> buf landed; syncs block
        if (s < 7) STAGE(s + 1, buf ^ 1);

        const float4* A4 = (const float4*)(smem + (buf ? 2048 : 0));
        const float4* B4 = (const float4*)(smem + 4096 + (buf ? 2048 : 0));
        #pragma unroll
        for (int cl = 0; cl < 16; ++cl) {
            float4 a0 = A4[cl * 32 + ra0];
            float4 a1 = A4[cl * 32 + ra1];
            float4 b0 = B4[cl * 32 + rb0];
            float4 b1 = B4[cl * 32 + rb1];
            float av[8] = {a0.x, a0.y, a0.z, a0.w, a1.x, a1.y, a1.z, a1.w};
            float bv[8] = {b0.x, b0.y, b0.z, b0.w, b1.x, b1.y, b1.z, b1.w};
            #pragma unroll
            for (int i = 0; i < 8; ++i)
                #pragma unroll
                for (int j = 0; j < 8; ++j)
                    acc[i][j] = fmaf(av[i], bv[j], acc[i][j]); // c-ascending
        }
    }

    // normal store: G[rowbase+ty*8+i][colbase+tx*8 .. +7]
    #pragma unroll
    for (int i = 0; i < 8; ++i) {
        int row = rowbase + ty * 8 + i;
        float4 o0 = {acc[i][0], acc[i][1], acc[i][2], acc[i][3]};
        float4 o1 = {acc[i][4], acc[i][5], acc[i][6], acc[i][7]};
        float4* dst = (float4*)&G[(size_t)row * Nn + colbase + tx * 8];
        dst[0] = o0;
        dst[1] = o1;
    }

    // transposed store for off-diagonal tiles (bitwise == computing tile
    // (ci,ri): fmaf multiply commutes)
    if (ri != ci) {
        #pragma unroll
        for (int j = 0; j < 8; ++j) {
            int row = colbase + tx * 8 + j;
            float4 o0 = {acc[0][j], acc[1][j], acc[2][j], acc[3][j]};
            float4 o1 = {acc[4][j], acc[5][j], acc[6][j], acc[7][j]};
            float4* dst = (float4*)&G[(size_t)row * Nn + rowbase + ty * 8];
            dst[0] = o0;
            dst[1] = o1;
        }
    }
}

// ---------------------------------------------------------------------------
// K2b (proven scan + batch decode): bb = bid>>12 (0 for per-batch tier).
// One block per row; 16 d2 candidates/thread in 4 named float4 regs;
// 9 branchless argmin-pop rounds per wave; wave 0 merges 36 values.
// d2 = fmaf(-2,G,sqr+sqc); diagonal exact 0 -> self always selected.
// ---------------------------------------------------------------------------
__global__ __launch_bounds__(256) void k_scan_all(
        const float* __restrict__ Gall, const float* __restrict__ sq,
        int* __restrict__ idxOut, int bbase) {
    const int t    = threadIdx.x;
    const int lane = t & 63;
    const int w    = t >> 6;                  // wave 0..3
    const int bb   = blockIdx.x >> 12;        // local batch
    const int row  = blockIdx.x & (Nn - 1);
    const int b    = bbase + bb;
    const float* sqb = sq + (size_t)b * Nn;
    const float sqr = sqb[row];

    const float4* G4  = (const float4*)(Gall + (size_t)bb * Nn * Nn + (size_t)row * Nn);
    const float4* sq4 = (const float4*)sqb;

    float4 d0, d1, d2v, d3;
    {
        float4 g, s;
        g = G4[t];        s = sq4[t];
        d0.x = fmaf(-2.f, g.x, sqr + s.x); d0.y = fmaf(-2.f, g.y, sqr + s.y);
        d0.z = fmaf(-2.f, g.z, sqr + s.z); d0.w = fmaf(-2.f, g.w, sqr + s.w);
        g = G4[256 + t];  s = sq4[256 + t];
        d1.x = fmaf(-2.f, g.x, sqr + s.x); d1.y = fmaf(-2.f, g.y, sqr + s.y);
        d1.z = fmaf(-2.f, g.z, sqr + s.z); d1.w = fmaf(-2.f, g.w, sqr + s.w);
        g = G4[512 + t];  s = sq4[512 + t];
        d2v.x = fmaf(-2.f, g.x, sqr + s.x); d2v.y = fmaf(-2.f, g.y, sqr + s.y);
        d2v.z = fmaf(-2.f, g.z, sqr + s.z); d2v.w = fmaf(-2.f, g.w, sqr + s.w);
        g = G4[768 + t];  s = sq4[768 + t];
        d3.x = fmaf(-2.f, g.x, sqr + s.x); d3.y = fmaf(-2.f, g.y, sqr + s.y);
        d3.z = fmaf(-2.f, g.z, sqr + s.z); d3.w = fmaf(-2.f, g.w, sqr + s.w);
    }

    float lv; int ls, lc;
    auto localmin = [&]() {
        float v = d0.x; int s = 0;
        #define MSTEP(val, id) { bool tk = (val) < v; v = tk ? (val) : v; s = tk ? (id) : s; }
        MSTEP(d0.y, 1)  MSTEP(d0.z, 2)  MSTEP(d0.w, 3)
        MSTEP(d1.x, 4)  MSTEP(d1.y, 5)  MSTEP(d1.z, 6)  MSTEP(d1.w, 7)
        MSTEP(d2v.x, 8) MSTEP(d2v.y, 9) MSTEP(d2v.z, 10) MSTEP(d2v.w, 11)
        MSTEP(d3.x, 12) MSTEP(d3.y, 13) MSTEP(d3.z, 14) MSTEP(d3.w, 15)
        #undef MSTEP
        lv = v; ls = s;
        lc = ((((s >> 2) * 256 + t) << 2) | (s & 3));   // global col
    };
    auto maskslot = [&]() {
        d0.x = (ls == 0)  ? INFF : d0.x;  d0.y = (ls == 1)  ? INFF : d0.y;
        d0.z = (ls == 2)  ? INFF : d0.z;  d0.w = (ls == 3)  ? INFF : d0.w;
        d1.x = (ls == 4)  ? INFF : d1.x;  d1.y = (ls == 5)  ? INFF : d1.y;
        d1.z = (ls == 6)  ? INFF : d1.z;  d1.w = (ls == 7)  ? INFF : d1.w;
        d2v.x = (ls == 8) ? INFF : d2v.x; d2v.y = (ls == 9)  ? INFF : d2v.y;
        d2v.z = (ls == 10)? INFF : d2v.z; d2v.w = (ls == 11) ? INFF : d2v.w;
        d3.x = (ls == 12) ? INFF : d3.x;  d3.y = (ls == 13) ? INFF : d3.y;
        d3.z = (ls == 14) ? INFF : d3.z;  d3.w = (ls == 15) ? INFF : d3.w;
    };

    localmin();

    __shared__ float ld[4][9];
    __shared__ int   li[4][9];

    #pragma unroll
    for (int k = 0; k < 9; ++k) {
        float v = lv; int i = lc;
        #pragma unroll
        for (int m = 32; m; m >>= 1) {
            float ov = __shfl_xor(v, m);
            int   oi = __shfl_xor(i, m);
            bool tk = (ov < v) || (ov == v && oi < i);
            v = tk ? ov : v;
            i = tk ? oi : i;
        }
        if (lane == 0) { ld[w][k] = v; li[w][k] = i; }
        if (lc == i) {                        // my candidate won: pop it
            maskslot();
            localmin();
        }
    }
    __syncthreads();

    if (w == 0) {
        float v36 = INFF; int i36 = 0x7fffffff;
        if (lane < 36) {
            int wl = lane / 9, kk = lane - wl * 9;
            v36 = ld[wl][kk];
            i36 = li[wl][kk];
        }
        #pragma unroll
        for (int k = 0; k < 9; ++k) {
            float v = v36; int i = i36;
            #pragma unroll
            for (int m = 32; m; m >>= 1) {
                float ov = __shfl_xor(v, m);
                int   oi = __shfl_xor(i, m);
                bool tk = (ov < v) || (ov == v && oi < i);
                v = tk ? ov : v;
                i = tk ? oi : i;
            }
            if (lane == 0)
                idxOut[((size_t)b * 9 + k) * Nn + row] = i;
            if (i36 == i) v36 = INFF;         // self-mask (cols unique)
        }
    }
}

// ===========================================================================
// FALLBACK PATH (r13, proven): fused gram+top9 + merge, if ws too small.
// ===========================================================================
__global__ __launch_bounds__(256, 1) void k_gram_topk(
        const float* __restrict__ x, const float* __restrict__ sq,
        float* __restrict__ pd, int* __restrict__ pi) {
    __shared__ alignas(16) float As[2][32 * 64];    // 2 x 8KB
    __shared__ alignas(16) float Bs[2][32 * 128];   // 2 x 16KB

    const int t  = threadIdx.x;
    const int tx = t & 15;
    const int ty = t >> 4;
    const int bid = blockIdx.x;               // (b*64 + rg)*8 + oct
    const int b   = bid >> 9;
    const int rg  = (bid >> 3) & 63;
    const int oct = bid & 7;
    const int rowbase = rg * 64;
    const int coloct = oct * 512;
    const float* xb  = x + (size_t)b * Cc * Nn;
    const float* sqb = sq + b * Nn;

    float rown[4];
    #pragma unroll
    for (int i = 0; i < 4; ++i) rown[i] = sqb[rowbase + ty * 4 + i];

    float cd[4][9]; int ci[4][9];
    #pragma unroll
    for (int i = 0; i < 4; ++i)
        #pragma unroll
        for (int p = 0; p < 9; ++p) { cd[i][p] = INFF; ci[i][p] = 0; }

    const int ra  = swz16(ty);
    const int rb0 = swz(tx * 2), rb1 = swz(tx * 2 + 1);

    auto STAGE = [&](int s, int buf) {
        const int c0 = (s & 3) * 32;
        const int colbase = coloct + (s >> 2) * 128;
        float* Ab = &As[buf][0];
        float* Bb = &Bs[buf][0];
        #pragma unroll
        for (int j = 0; j < 2; ++j) {
            int f = j * 256 + t;
            int cl = f >> 4, q = f & 15;
            int qi = (q & 8) | ((q - (q >> 3)) & 7);
            gload16(&xb[(size_t)(c0 + cl) * Nn + rowbase + qi * 4],
                    &Ab[(f & ~63) * 4]);
        }
        #pragma unroll
        for (int j = 0; j < 4; ++j) {
            int f = j * 256 + t;
            int cl = f >> 5, q = f & 31;
            int qi = (q & 24) | ((q - (q >> 3)) & 7);
            gload16(&xb[(size_t)(c0 + cl) * Nn + colbase + qi * 4],
                    &Bb[(f & ~63) * 4]);
        }
    };

    STAGE(0, 0);
    float acc[4][8];
    for (int s = 0; s < 16; ++s) {
        const int buf = s & 1;
        __syncthreads();
        if (s < 15) STAGE(s + 1, buf ^ 1);

        if ((s & 3) == 0) {
            #pragma unroll
            for (int i = 0; i < 4; ++i)
                #pragma unroll
                for (int j = 0; j < 8; ++j) acc[i][j] = 0.f;
        }

        const float4* A4 = (const float4*)&As[buf][0];
        const float4* B4 = (const float4*)&Bs[buf][0];
        #pragma unroll 4
        for (int cl = 0; cl < 32; ++cl) {
            float4 a  = A4[cl * 16 + ra];
            float4 b0 = B4[cl * 32 + rb0];
            float4 b1 = B4[cl * 32 + rb1];
            float av[4] = {a.x, a.y, a.z, a.w};
            float bv[8] = {b0.x, b0.y, b0.z, b0.w, b1.x, b1.y, b1.z, b1.w};
            #pragma unroll
            for (int i = 0; i < 4; ++i)
                #pragma unroll
                for (int j = 0; j < 8; ++j)
                    acc[i][j] = fmaf(av[i], bv[j], acc[i][j]);
        }

        if ((s & 3) == 3) {
            const int colbase = coloct + (s >> 2) * 128;
            float4 cn0 = *(const float4*)&sqb[colbase + tx * 8];
            float4 cn1 = *(const float4*)&sqb[colbase + tx * 8 + 4];
            float cn[8] = {cn0.x, cn0.y, cn0.z, cn0.w,
                           cn1.x, cn1.y, cn1.z, cn1.w};
            #pragma unroll
            for (int i = 0; i < 4; ++i)
                #pragma unroll
                for (int j = 0; j < 8; ++j) {
                    float dd = fmaf(-2.0f, acc[i][j], rown[i] + cn[j]);
                    if (dd < cd[i][8])
                        insert9(cd[i], ci[i], dd, colbase + tx * 8 + j);
                }
        }
    }

    #pragma unroll
    for (int m = 1; m < 16; m <<= 1) {
        #pragma unroll
        for (int i = 0; i < 4; ++i) {
            float od[9]; int oi[9];
            #pragma unroll
            for (int p = 0; p < 9; ++p) {
                od[p] = __shfl_xor(cd[i][p], m);
                oi[p] = __shfl_xor(ci[i][p], m);
            }
            #pragma unroll
            for (int p = 0; p < 9; ++p)
                if (od[p] < cd[i][8]) insert9(cd[i], ci[i], od[p], oi[p]);
        }
    }

    if (tx == 0) {
        #pragma unroll
        for (int i = 0; i < 4; ++i) {
            int n = rowbase + ty * 4 + i;
            #pragma unroll
            for (int k = 0; k < 9; ++k) {
                size_t o = (((size_t)b * 8 + oct) * 9 + k) * Nn + n;
                pd[o] = cd[i][k];
                pi[o] = ci[i][k];
            }
        }
    }
}

__global__ void k_merge(const float* __restrict__ pd, const int* __restrict__ pi,
                        int* __restrict__ idxOut) {
    int id = blockIdx.x * 256 + threadIdx.x;  // 16384
    int b = id >> 12, n = id & (Nn - 1);
    float d0[9]; int i0[9];
    #pragma unroll
    for (int k = 0; k < 9; ++k) {
        size_t o = (((size_t)b * 8 + 0) * 9 + k) * Nn + n;
        d0[k] = pd[o]; i0[k] = pi[o];
    }
    #pragma unroll
    for (int q = 1; q < 8; ++q) {
        #pragma unroll
        for (int k = 0; k < 9; ++k) {
            size_t o = (((size_t)b * 8 + q) * 9 + k) * Nn + n;
            float dv = pd[o]; int iv = pi[o];
            if (dv < d0[8]) insert9(d0, i0, dv, iv);
        }
    }
    #pragma unroll
    for (int k = 0; k < 9; ++k)
        idxOut[((size_t)b * 9 + k) * Nn + n] = i0[k];
}

// ---------------------------------------------------------------------------
// K3: h0[b][c][n] = (1+eps)*x[b][c][n] + sum_k x[b][c][idx[b][k][n]]
// ---------------------------------------------------------------------------
__global__ void k_gather(const float* __restrict__ x, const int* __restrict__ idx,
                         const float* __restrict__ epsp, float* __restrict__ h0) {
    int id = blockIdx.x * 256 + threadIdx.x;          // B*C*N = 2097152
    int n  = id & (Nn - 1);
    int bc = id >> 12;                                // b*C + c
    int b  = bc >> 7;
    const float* xr = x + (size_t)bc * Nn;
    const int* ib = idx + (size_t)b * 9 * Nn + n;
    float s = (1.0f + epsp[0]) * xr[n];
    #pragma unroll
    for (int k = 0; k < 9; ++k) s += xr[ib[(size_t)k * Nn]];
    h0[id] = s;
}

// ---------------------------------------------------------------------------
// K4/K5: out[b][d][n] = act( bias[d] + sum_c W[c][d] * in[b][c][n] )
// ---------------------------------------------------------------------------
template <bool RELU>
__global__ __launch_bounds__(256, 2) void k_mlp(
        const float* __restrict__ in, const float* __restrict__ W,
        const float* __restrict__ bias, float* __restrict__ out) {
    const int t  = threadIdx.x;
    const int td = t & 15;
    const int tn = t >> 4;
    const int bid = blockIdx.x;   // B*2*64 = 512
    const int b = bid >> 7;
    const int dbase = ((bid >> 6) & 1) * 64;
    const int nb = (bid & 63) * 64;

    __shared__ alignas(16) float Ws[128 * 64];
    __shared__ alignas(16) float Hs[128 * 64];

    for (int k = t; k < 128 * 64; k += 256) {
        int i = k & 63; int c = k >> 6;
        int sw = c * 64 + ((((i >> 2) ^ (c & 7)) << 2) | (i & 3));
        Ws[sw] = W[c * 128 + dbase + i];
        Hs[sw] = in[((size_t)b * 128 + c) * Nn + nb + i];
    }
    __syncthreads();

    float acc[4][4];
    #pragma unroll
    for (int dd = 0; dd < 4; ++dd)
        #pragma unroll
        for (int nn = 0; nn < 4; ++nn) acc[dd][nn] = 0.f;

    const float4* W4 = reinterpret_cast<const float4*>(Ws);
    const float4* H4 = reinterpret_cast<const float4*>(Hs);
    for (int c = 0; c < 128; ++c) {
        int cx = c & 7;
        float4 w = W4[c * 16 + (td ^ cx)];
        float4 h = H4[c * 16 + (tn ^ cx)];
        float wf[4] = {w.x, w.y, w.z, w.w};
        float hf[4] = {h.x, h.y, h.z, h.w};
        #pragma unroll
        for (int dd = 0; dd < 4; ++dd)
            #pragma unroll
            for (int nn = 0; nn < 4; ++nn)
                acc[dd][nn] = fmaf(wf[dd], hf[nn], acc[dd][nn]);
    }

    #pragma unroll
    for (int dd = 0; dd < 4; ++dd) {
        int d = dbase + 4 * td + dd;
        float bb = bias[d];
        float4 o;
        o.x = acc[dd][0] + bb; o.y = acc[dd][1] + bb;
        o.z = acc[dd][2] + bb; o.w = acc[dd][3] + bb;
        if (RELU) {
            o.x = fmaxf(o.x, 0.f); o.y = fmaxf(o.y, 0.f);
            o.z = fmaxf(o.z, 0.f); o.w = fmaxf(o.w, 0.f);
        }
        *reinterpret_cast<float4*>(&out[((size_t)b * 128 + d) * Nn + nb + 4 * tn]) = o;
    }
}

// ---------------------------------------------------------------------------
// K6: per-channel batch-norm stats (biased var), 1 block per channel.
// ---------------------------------------------------------------------------
__global__ void k_bnstats(const float* __restrict__ o, const float* __restrict__ gamma,
                          const float* __restrict__ beta, float* __restrict__ scsh) {
    int e = blockIdx.x, t = threadIdx.x;
    float s = 0.f, s2 = 0.f;
    for (int b = 0; b < Bc; ++b) {
        const float* p = o + ((size_t)b * 128 + e) * Nn;
        for (int n = t; n < Nn; n += 256) {
            float v = p[n];
            s += v;
            s2 = fmaf(v, v, s2);
        }
    }
    __shared__ float rs[256], rq[256];
    rs[t] = s; rq[t] = s2;
    __syncthreads();
    for (int off = 128; off > 0; off >>= 1) {
        if (t < off) { rs[t] += rs[t + off]; rq[t] += rq[t + off]; }
        __syncthreads();
    }
    if (t == 0) {
        float mean = rs[0] * (1.0f / 16384.0f);
        float var  = rq[0] * (1.0f / 16384.0f) - mean * mean;
        if (var < 0.f) var = 0.f;
        float sc = gamma[e] * rsqrtf(var + 1e-5f);
        scsh[e] = sc;
        scsh[128 + e] = beta[e] - mean * sc;
    }
}

// ---------------------------------------------------------------------------
// K7: out = relu(scale[e]*o + shift[e] + x), in place on d_out, float4.
// ---------------------------------------------------------------------------
__global__ void k_bnapply(float* __restrict__ o, const float* __restrict__ x,
                          const float* __restrict__ scsh) {
    int id4 = blockIdx.x * 256 + threadIdx.x;         // 524288
    int e = (id4 >> 10) & 127;
    float sc = scsh[e], sh = scsh[128 + e];
    float4 v = reinterpret_cast<const float4*>(o)[id4];
    float4 r = reinterpret_cast<const float4*>(x)[id4];
    float4 w;
    w.x = fmaxf(fmaf(sc, v.x, sh) + r.x, 0.f);
    w.y = fmaxf(fmaf(sc, v.y, sh) + r.y, 0.f);
    w.z = fmaxf(fmaf(sc, v.z, sh) + r.z, 0.f);
    w.w = fmaxf(fmaf(sc, v.w, sh) + r.w, 0.f);
    reinterpret_cast<float4*>(o)[id4] = w;
}

// ---------------------------------------------------------------------------
extern "C" void kernel_launch(void* const* d_in, const int* in_sizes, int n_in,
                              void* d_out, int out_size, void* d_ws, size_t ws_size,
                              hipStream_t stream) {
    const float* x     = (const float*)d_in[0];
    const float* epsp  = (const float*)d_in[1];
    const float* W1    = (const float*)d_in[2];
    const float* b1    = (const float*)d_in[3];
    const float* W2    = (const float*)d_in[4];
    const float* b2    = (const float*)d_in[5];
    const float* gamma = (const float*)d_in[6];
    const float* beta  = (const float*)d_in[7];
    float* out = (float*)d_out;

    // common layout (floats): sq[16384] | idx[147456] | h0[2097152] |
    // h1[2097152] | scsh[256] = 4358400 floats (~16.6MB)
    float* ws   = (float*)d_ws;
    float* sq   = ws;
    int*   idx  = (int*)(ws + 16384);
    float* h0   = ws + 16384 + (size_t)Bc * 9 * Nn;
    float* h1   = h0 + (size_t)Bc * Cc * Nn;
    float* scsh = h1 + (size_t)Bc * Cc * Nn;
    float* G    = ws + 4358400;               // 1..4 x [4096][4096]

    const size_t base  = 4358400ull * 4;
    const size_t gsz   = (size_t)Nn * Nn * 4;            // 67.1MB
    const size_t need4 = base + 4 * gsz;                 // ~285MB
    const size_t need2 = base + 2 * gsz;                 // ~151MB
    const size_t need1 = base + gsz;                     // ~84.5MB

    k_sq <<<64, 256, 0, stream>>>(x, sq);

    if (ws_size >= need4) {
        // fully batched: one gemm dispatch (grid 2112), one scan (16384).
        k_gemm_all<<<2112,  256, 0, stream>>>(x, G);
        k_scan_all<<<16384, 256, 0, stream>>>(G, sq, idx, 0);
    } else if (ws_size >= need2) {
        // 2-batch tier: grid 1056 gemm + grid 8192 scan, twice.
        for (int g = 0; g < 2; ++g) {
            k_gemm_all<<<1056, 256, 0, stream>>>(x + (size_t)(g * 2) * Cc * Nn, G);
            k_scan_all<<<8192, 256, 0, stream>>>(G, sq, idx, g * 2);
        }
    } else if (ws_size >= need1) {
        // r18 per-batch tier (proven 413us).
        for (int b = 0; b < Bc; ++b) {
            k_gemm_all<<<528,  256, 0, stream>>>(x + (size_t)b * Cc * Nn, G);
            k_scan_all<<<4096, 256, 0, stream>>>(G, sq, idx, b);
        }
    } else {
        // fused fallback (r13, proven): pd aliases h0, pi aliases h1
        float* pd = h0;
        int*   pi = (int*)h1;
        k_gram_topk<<<2048, 256, 0, stream>>>(x, sq, pd, pi);
        k_merge    <<<64,   256, 0, stream>>>(pd, pi, idx);
    }

    k_gather    <<<8192, 256, 0, stream>>>(x, idx, epsp, h0);
    k_mlp<true> <<<512,  256, 0, stream>>>(h0, W1, b1, h1);
    k_mlp<false><<<512,  256, 0, stream>>>(h1, W2, b2, out);
    k_bnstats   <<<128,  256, 0, stream>>>(out, gamma, beta, scsh);
    k_bnapply   <<<2048, 256, 0, stream>>>(out, x, scsh);
}